// Round 1
// baseline (666.508 us; speedup 1.0000x reference)
//
#include <hip/hip_runtime.h>

#define N_NODES 50000
#define N_EDGES 1600000
#define IN_DIM 6
#define H 64

// ---------------------------------------------------------------------------
// Kernel A: layer-1 edge aggregation.
// One thread per (edge, slot) with 8 slots/edge: slots 0..5 accumulate the
// 6-dim feature, slot 6 accumulates the degree count, slot 7 idle.
// ---------------------------------------------------------------------------
__global__ void agg1_kernel(const float* __restrict__ x,
                            const int* __restrict__ ei,
                            float* __restrict__ agg1,
                            float* __restrict__ cnt) {
    int tid = blockIdx.x * blockDim.x + threadIdx.x;
    int e = tid >> 3;
    int j = tid & 7;
    if (e >= N_EDGES) return;
    int src = ei[e];
    int dst = ei[N_EDGES + e];
    if (j < IN_DIM) {
        atomicAdd(&agg1[dst * IN_DIM + j], x[src * IN_DIM + j]);
    } else if (j == IN_DIM) {
        atomicAdd(&cnt[dst], 1.0f);
    }
}

// ---------------------------------------------------------------------------
// Kernel B: layer-1 node update.  z = relu(mean1 @ W1_l + b1 + x @ W1_r)
// 256 threads/block = 4 nodes, 64 threads (one output feature each) per node.
// W1_l / W1_r (6x64 each) staged in LDS.
// ---------------------------------------------------------------------------
__global__ void layer1_kernel(const float* __restrict__ x,
                              const float* __restrict__ agg1,
                              const float* __restrict__ cnt,
                              const float* __restrict__ W1l,
                              const float* __restrict__ b1,
                              const float* __restrict__ W1r,
                              float* __restrict__ z) {
    __shared__ float sWl[IN_DIM * H];
    __shared__ float sWr[IN_DIM * H];
    int t = threadIdx.x;
    for (int i = t; i < IN_DIM * H; i += 256) {
        sWl[i] = W1l[i];
        sWr[i] = W1r[i];
    }
    __syncthreads();

    int local = t >> 6;      // 0..3
    int h = t & 63;          // output feature
    int n = blockIdx.x * 4 + local;
    if (n >= N_NODES) return;

    float inv = 1.0f / fmaxf(cnt[n], 1.0f);
    float acc = b1[h];
#pragma unroll
    for (int k = 0; k < IN_DIM; k++) {
        float m = agg1[n * IN_DIM + k] * inv;   // broadcast within the 64 lanes
        float xv = x[n * IN_DIM + k];
        acc += m * sWl[k * H + h] + xv * sWr[k * H + h];
    }
    z[n * H + h] = fmaxf(acc, 0.0f);
}

// ---------------------------------------------------------------------------
// Kernel C: layer-2 edge aggregation.  One 64-lane wave per edge:
// coalesced 256B read of z[src], 64 coalesced atomicAdds into agg2[dst].
// ---------------------------------------------------------------------------
__global__ void agg2_kernel(const float* __restrict__ z,
                            const int* __restrict__ ei,
                            float* __restrict__ agg2) {
    int tid = blockIdx.x * blockDim.x + threadIdx.x;
    int e = tid >> 6;
    int h = tid & 63;
    if (e >= N_EDGES) return;
    int src = ei[e];
    int dst = ei[N_EDGES + e];
    atomicAdd(&agg2[dst * H + h], z[src * H + h]);
}

// ---------------------------------------------------------------------------
// Kernel D: layer-2 node update.  out = mean2 @ W2_l + b2 + z @ W2_r
// 256 threads/block = 4 nodes.  W2_l/W2_r (64x64 each, 32KB) in LDS;
// per-node mean2/z rows staged in LDS for broadcast in the k-loop.
// ---------------------------------------------------------------------------
__global__ void layer2_kernel(const float* __restrict__ z,
                              const float* __restrict__ agg2,
                              const float* __restrict__ cnt,
                              const float* __restrict__ W2l,
                              const float* __restrict__ b2,
                              const float* __restrict__ W2r,
                              float* __restrict__ out) {
    __shared__ float sWl[H * H];
    __shared__ float sWr[H * H];
    __shared__ float sm[4][H];
    __shared__ float sz[4][H];
    int t = threadIdx.x;
    for (int i = t; i < H * H; i += 256) {
        sWl[i] = W2l[i];
        sWr[i] = W2r[i];
    }

    int local = t >> 6;
    int h = t & 63;
    int n = blockIdx.x * 4 + local;
    bool valid = (n < N_NODES);
    if (valid) {
        float inv = 1.0f / fmaxf(cnt[n], 1.0f);
        sm[local][h] = agg2[n * H + h] * inv;
        sz[local][h] = z[n * H + h];
    }
    __syncthreads();
    if (!valid) return;

    float acc = b2[h];
#pragma unroll
    for (int k = 0; k < H; k++) {
        acc += sm[local][k] * sWl[k * H + h] + sz[local][k] * sWr[k * H + h];
    }
    out[n * H + h] = acc;
}

// ---------------------------------------------------------------------------
extern "C" void kernel_launch(void* const* d_in, const int* in_sizes, int n_in,
                              void* d_out, int out_size, void* d_ws, size_t ws_size,
                              hipStream_t stream) {
    const float* x    = (const float*)d_in[0];
    const int*   ei   = (const int*)d_in[1];   // [2, N_EDGES] int32
    const float* W1l  = (const float*)d_in[2];
    const float* b1   = (const float*)d_in[3];
    const float* W1r  = (const float*)d_in[4];
    const float* W2l  = (const float*)d_in[5];
    const float* b2   = (const float*)d_in[6];
    const float* W2r  = (const float*)d_in[7];
    float* out = (float*)d_out;

    // Workspace layout (floats):
    float* ws   = (float*)d_ws;
    float* cnt  = ws;                      // 50000
    float* agg1 = ws + 50000;              // 300000
    float* z    = ws + 350000;             // 3200000
    float* agg2 = ws + 3550000;            // 3200000

    // Zero the accumulators (ws is poisoned 0xAA before every timed launch).
    hipMemsetAsync(cnt, 0, (size_t)(50000 + 300000) * sizeof(float), stream);
    hipMemsetAsync(agg2, 0, (size_t)3200000 * sizeof(float), stream);

    // A: layer-1 edge aggregation: E*8 threads
    {
        int threads = N_EDGES * 8;
        int blocks = (threads + 255) / 256;
        agg1_kernel<<<blocks, 256, 0, stream>>>(x, ei, agg1, cnt);
    }
    // B: layer-1 node update
    {
        int blocks = (N_NODES + 3) / 4;
        layer1_kernel<<<blocks, 256, 0, stream>>>(x, agg1, cnt, W1l, b1, W1r, z);
    }
    // C: layer-2 edge aggregation: E*64 threads
    {
        long long threads = (long long)N_EDGES * 64;
        int blocks = (int)((threads + 255) / 256);
        agg2_kernel<<<blocks, 256, 0, stream>>>(z, ei, agg2);
    }
    // D: layer-2 node update
    {
        int blocks = (N_NODES + 3) / 4;
        layer2_kernel<<<blocks, 256, 0, stream>>>(z, agg2, cnt, W2l, b2, W2r, out);
    }
}

// Round 2
// 554.260 us; speedup vs baseline: 1.2025x; 1.2025x over previous
//
#include <hip/hip_runtime.h>

#define N_NODES 50000
#define N_EDGES 1600000
#define IN_DIM 6
#define H 64

// ---------------------------------------------------------------------------
// CSR build, step 1: degree histogram over dst.
// ---------------------------------------------------------------------------
__global__ void hist_kernel(const int* __restrict__ ei, int* __restrict__ deg) {
    int e = blockIdx.x * blockDim.x + threadIdx.x;
    if (e >= N_EDGES) return;
    atomicAdd(&deg[ei[N_EDGES + e]], 1);
}

// ---------------------------------------------------------------------------
// CSR build, step 2: exclusive scan of deg[N_NODES] -> rowstart[N_NODES+1].
// Single 1024-thread block; wave-shuffle scan + cross-wave LDS scan.
// ---------------------------------------------------------------------------
__global__ __launch_bounds__(1024) void scan_kernel(const int* __restrict__ deg,
                                                    int* __restrict__ rowstart) {
    __shared__ int wsum[16];
    __shared__ int woff[16];
    __shared__ int s_carry;
    int t = threadIdx.x;
    int lane = t & 63, wid = t >> 6;
    if (t == 0) s_carry = 0;
    __syncthreads();
    for (int base = 0; base < N_NODES; base += 1024) {
        int i = base + t;
        int v = (i < N_NODES) ? deg[i] : 0;
        int s = v;
#pragma unroll
        for (int off = 1; off < 64; off <<= 1) {
            int u = __shfl_up(s, off);
            if (lane >= off) s += u;
        }
        if (lane == 63) wsum[wid] = s;
        __syncthreads();
        if (t == 0) {
            int acc = 0;
#pragma unroll
            for (int w = 0; w < 16; w++) { woff[w] = acc; acc += wsum[w]; }
            wsum[0] = acc;  // chunk total
        }
        __syncthreads();
        if (i < N_NODES) rowstart[i] = s_carry + woff[wid] + s - v;
        __syncthreads();                 // everyone has consumed s_carry
        if (t == 0) s_carry += wsum[0];
        __syncthreads();
    }
    if (t == 0) rowstart[N_NODES] = s_carry;
}

// ---------------------------------------------------------------------------
// CSR build, step 3: scatter src indices into dst buckets.
// cursor[] is pre-initialized to rowstart[] (D2D copy).
// ---------------------------------------------------------------------------
__global__ void scatter_kernel(const int* __restrict__ ei,
                               int* __restrict__ cursor,
                               int* __restrict__ esrc) {
    int e = blockIdx.x * blockDim.x + threadIdx.x;
    if (e >= N_EDGES) return;
    int src = ei[e];
    int dst = ei[N_EDGES + e];
    int pos = atomicAdd(&cursor[dst], 1);
    esrc[pos] = src;
}

// ---------------------------------------------------------------------------
// Layer 1 fused: per-node neighbor mean of x (6-dim) + linear + relu.
// One wave per node, 4 waves / block.  N_NODES = 50000 = 12500*4 exactly,
// so no early-exit (safe to __syncthreads anywhere).
// ---------------------------------------------------------------------------
__global__ __launch_bounds__(256) void layer1_fused(
        const float* __restrict__ x,
        const int* __restrict__ rowstart,
        const int* __restrict__ esrc,
        const float* __restrict__ W1l,
        const float* __restrict__ b1,
        const float* __restrict__ W1r,
        float* __restrict__ z) {
    __shared__ float sWl[IN_DIM * H];
    __shared__ float sWr[IN_DIM * H];
    int t = threadIdx.x;
    for (int i = t; i < IN_DIM * H; i += 256) {
        sWl[i] = W1l[i];
        sWr[i] = W1r[i];
    }
    __syncthreads();

    int wid = t >> 6, lane = t & 63;
    int n = blockIdx.x * 4 + wid;
    int r0 = rowstart[n], r1 = rowstart[n + 1];

    float a0 = 0.f, a1 = 0.f, a2 = 0.f, a3 = 0.f, a4 = 0.f, a5 = 0.f;
    for (int i = r0 + lane; i < r1; i += 64) {
        const float* xs = x + (long long)esrc[i] * IN_DIM;
        a0 += xs[0]; a1 += xs[1]; a2 += xs[2];
        a3 += xs[3]; a4 += xs[4]; a5 += xs[5];
    }
    // butterfly all-reduce across the wave
#pragma unroll
    for (int off = 1; off < 64; off <<= 1) {
        a0 += __shfl_xor(a0, off);
        a1 += __shfl_xor(a1, off);
        a2 += __shfl_xor(a2, off);
        a3 += __shfl_xor(a3, off);
        a4 += __shfl_xor(a4, off);
        a5 += __shfl_xor(a5, off);
    }
    float inv = 1.0f / fmaxf((float)(r1 - r0), 1.0f);
    float m[IN_DIM] = {a0 * inv, a1 * inv, a2 * inv, a3 * inv, a4 * inv, a5 * inv};

    const float* xn = x + (long long)n * IN_DIM;
    int h = lane;
    float acc = b1[h];
#pragma unroll
    for (int k = 0; k < IN_DIM; k++) {
        acc += m[k] * sWl[k * H + h] + xn[k] * sWr[k * H + h];
    }
    z[(long long)n * H + h] = fmaxf(acc, 0.0f);
}

// ---------------------------------------------------------------------------
// Layer 2 fused: per-node neighbor mean of z (64-dim) + linear.
// One wave per node, lane = output feature.  Neighbor rows read coalesced
// (256 B per edge); indices batch-loaded then shfl-broadcast.
// ---------------------------------------------------------------------------
__global__ __launch_bounds__(256) void layer2_fused(
        const float* __restrict__ zin,
        const int* __restrict__ rowstart,
        const int* __restrict__ esrc,
        const float* __restrict__ W2l,
        const float* __restrict__ b2,
        const float* __restrict__ W2r,
        float* __restrict__ out) {
    __shared__ float sWl[H * H];
    __shared__ float sWr[H * H];
    __shared__ float smrow[4][H];
    __shared__ float szrow[4][H];
    int t = threadIdx.x;
    for (int i = t; i < H * H; i += 256) {
        sWl[i] = W2l[i];
        sWr[i] = W2r[i];
    }

    int wid = t >> 6, lane = t & 63;
    int n = blockIdx.x * 4 + wid;
    int r0 = rowstart[n], r1 = rowstart[n + 1];

    float acc = 0.f;
    int i = r0;
    while (i < r1) {
        int cnt = r1 - i;
        if (cnt >= 64) {
            int myidx = esrc[i + lane];          // coalesced batch of 64 indices
#pragma unroll 8
            for (int j = 0; j < 64; j++) {
                int s = __shfl(myidx, j);
                acc += zin[(long long)s * H + lane];
            }
            i += 64;
        } else {
            int myidx = (lane < cnt) ? esrc[i + lane] : 0;
            for (int j = 0; j < cnt; j++) {
                int s = __shfl(myidx, j);
                acc += zin[(long long)s * H + lane];
            }
            i += cnt;
        }
    }
    float inv = 1.0f / fmaxf((float)(r1 - r0), 1.0f);
    smrow[wid][lane] = acc * inv;
    szrow[wid][lane] = zin[(long long)n * H + lane];
    __syncthreads();   // covers weight staging too; all threads always reach

    float r = b2[lane];
#pragma unroll
    for (int k = 0; k < H; k++) {
        r += smrow[wid][k] * sWl[k * H + lane] + szrow[wid][k] * sWr[k * H + lane];
    }
    out[(long long)n * H + lane] = r;
}

// ---------------------------------------------------------------------------
extern "C" void kernel_launch(void* const* d_in, const int* in_sizes, int n_in,
                              void* d_out, int out_size, void* d_ws, size_t ws_size,
                              hipStream_t stream) {
    const float* x   = (const float*)d_in[0];
    const int*   ei  = (const int*)d_in[1];   // [2, N_EDGES]
    const float* W1l = (const float*)d_in[2];
    const float* b1  = (const float*)d_in[3];
    const float* W1r = (const float*)d_in[4];
    const float* W2l = (const float*)d_in[5];
    const float* b2  = (const float*)d_in[6];
    const float* W2r = (const float*)d_in[7];
    float* out = (float*)d_out;

    // Workspace layout:
    //   deg      : int[50000]
    //   rowstart : int[50001]
    //   cursor   : int[50000]
    //   esrc     : int[1600000]
    //   z        : float[3200000]
    int*   deg      = (int*)d_ws;
    int*   rowstart = deg + N_NODES;
    int*   cursor   = rowstart + N_NODES + 1;
    int*   esrc     = cursor + N_NODES;
    float* z        = (float*)(esrc + N_EDGES);

    hipMemsetAsync(deg, 0, (size_t)N_NODES * sizeof(int), stream);

    // CSR build
    {
        int blocks = (N_EDGES + 255) / 256;
        hist_kernel<<<blocks, 256, 0, stream>>>(ei, deg);
    }
    scan_kernel<<<1, 1024, 0, stream>>>(deg, rowstart);
    hipMemcpyAsync(cursor, rowstart, (size_t)N_NODES * sizeof(int),
                   hipMemcpyDeviceToDevice, stream);
    {
        int blocks = (N_EDGES + 255) / 256;
        scatter_kernel<<<blocks, 256, 0, stream>>>(ei, cursor, esrc);
    }

    // Fused layers (one wave per node; 50000 = 12500 * 4 exactly)
    layer1_fused<<<N_NODES / 4, 256, 0, stream>>>(x, rowstart, esrc, W1l, b1, W1r, z);
    layer2_fused<<<N_NODES / 4, 256, 0, stream>>>(z, rowstart, esrc, W2l, b2, W2r, out);
}

// Round 3
// 380.613 us; speedup vs baseline: 1.7511x; 1.4562x over previous
//
#include <hip/hip_runtime.h>

#define N_NODES 50000
#define N_EDGES 1600000
#define IN_DIM 6
#define H 64
#define SCAN_BLOCKS ((N_NODES + 255) / 256)   // 196

// ---------------------------------------------------------------------------
// CSR build, step 1: degree histogram over dst.
// ---------------------------------------------------------------------------
__global__ void hist_kernel(const int* __restrict__ ei, int* __restrict__ deg) {
    int e = blockIdx.x * blockDim.x + threadIdx.x;
    if (e >= N_EDGES) return;
    atomicAdd(&deg[ei[N_EDGES + e]], 1);
}

// ---------------------------------------------------------------------------
// Generic per-block exclusive scan of `in[n]` -> `out`, block totals -> sums[b].
// 256 threads/block, 4 waves: shfl-scan within wave + LDS cross-wave.
// ---------------------------------------------------------------------------
__global__ __launch_bounds__(256) void scan_local(const int* __restrict__ in,
                                                  int* __restrict__ out,
                                                  int* __restrict__ sums,
                                                  int n) {
    __shared__ int wsum[4];
    int t = threadIdx.x, lane = t & 63, w = t >> 6;
    int i = blockIdx.x * 256 + t;
    int v = (i < n) ? in[i] : 0;
    int s = v;
#pragma unroll
    for (int off = 1; off < 64; off <<= 1) {
        int u = __shfl_up(s, off);
        if (lane >= off) s += u;
    }
    if (lane == 63) wsum[w] = s;
    __syncthreads();
    int woff = 0;
    for (int k = 0; k < w; k++) woff += wsum[k];
    if (i < n) out[i] = s - v + woff;
    if (t == 255) sums[blockIdx.x] = woff + s;
}

// ---------------------------------------------------------------------------
// Scan step 3: add block offsets; also initialize cursor = rowstart.
// ---------------------------------------------------------------------------
__global__ void scan_add(int* __restrict__ rowstart,
                         int* __restrict__ cursor,
                         const int* __restrict__ blockoff) {
    int i = blockIdx.x * 256 + threadIdx.x;
    if (i < N_NODES) {
        int r = rowstart[i] + blockoff[blockIdx.x];
        rowstart[i] = r;
        cursor[i] = r;
    }
}

// ---------------------------------------------------------------------------
// CSR build, step 4: scatter src indices into dst buckets.
// ---------------------------------------------------------------------------
__global__ void scatter_kernel(const int* __restrict__ ei,
                               int* __restrict__ cursor,
                               int* __restrict__ esrc) {
    int e = blockIdx.x * blockDim.x + threadIdx.x;
    if (e >= N_EDGES) return;
    int src = ei[e];
    int dst = ei[N_EDGES + e];
    int pos = atomicAdd(&cursor[dst], 1);
    esrc[pos] = src;
}

// ---------------------------------------------------------------------------
// Layer 1 fused: per-node neighbor mean of x (6-dim) + linear + relu.
// One wave per node; x is 1.2 MB (L2-resident), gathers are cheap.
// ---------------------------------------------------------------------------
__global__ __launch_bounds__(256) void layer1_fused(
        const float* __restrict__ x,
        const int* __restrict__ rowstart,
        const int* __restrict__ esrc,
        const float* __restrict__ W1l,
        const float* __restrict__ b1,
        const float* __restrict__ W1r,
        float* __restrict__ z) {
    __shared__ float sWl[IN_DIM * H];
    __shared__ float sWr[IN_DIM * H];
    int t = threadIdx.x;
    for (int i = t; i < IN_DIM * H; i += 256) {
        sWl[i] = W1l[i];
        sWr[i] = W1r[i];
    }
    __syncthreads();

    int wid = t >> 6, lane = t & 63;
    int n = blockIdx.x * 4 + wid;
    int r0 = rowstart[n], r1 = rowstart[n + 1];

    float a0 = 0.f, a1 = 0.f, a2 = 0.f, a3 = 0.f, a4 = 0.f, a5 = 0.f;
    for (int i = r0 + lane; i < r1; i += 64) {
        const float* xs = x + (size_t)esrc[i] * IN_DIM;
        a0 += xs[0]; a1 += xs[1]; a2 += xs[2];
        a3 += xs[3]; a4 += xs[4]; a5 += xs[5];
    }
#pragma unroll
    for (int off = 1; off < 64; off <<= 1) {
        a0 += __shfl_xor(a0, off);
        a1 += __shfl_xor(a1, off);
        a2 += __shfl_xor(a2, off);
        a3 += __shfl_xor(a3, off);
        a4 += __shfl_xor(a4, off);
        a5 += __shfl_xor(a5, off);
    }
    float inv = 1.0f / fmaxf((float)(r1 - r0), 1.0f);
    float m[IN_DIM] = {a0 * inv, a1 * inv, a2 * inv, a3 * inv, a4 * inv, a5 * inv};

    const float* xn = x + (size_t)n * IN_DIM;
    int h = lane;
    float acc = b1[h];
#pragma unroll
    for (int k = 0; k < IN_DIM; k++) {
        acc += m[k] * sWl[k * H + h] + xn[k] * sWr[k * H + h];
    }
    z[(size_t)n * H + h] = fmaxf(acc, 0.0f);
}

// ---------------------------------------------------------------------------
// Layer 2 fused: per-node neighbor mean of z (64-dim) + linear.
// One wave per node.  Gather restructured for MLP: 4 groups of 16 lanes,
// each group reads one z-row per sub-iter as float4 (16 x 16B = 256B).
// Chunks of 16 edges with 4 unrolled sub-iters -> 4 independent float4
// loads in flight per lane.  Out-of-range edge slots clamp to the zero
// row at index N_NODES (L2-hot, cheap).
// ---------------------------------------------------------------------------
__global__ __launch_bounds__(256) void layer2_fused(
        const float* __restrict__ zin,
        const int* __restrict__ rowstart,
        const int* __restrict__ esrc,
        const float* __restrict__ W2l,
        const float* __restrict__ b2,
        const float* __restrict__ W2r,
        float* __restrict__ out) {
    __shared__ float sWl[H * H];
    __shared__ float sWr[H * H];
    __shared__ float smrow[4][H];
    __shared__ float szrow[4][H];
    int t = threadIdx.x;
    for (int i = t; i < H * H; i += 256) {
        sWl[i] = W2l[i];
        sWr[i] = W2r[i];
    }

    int wid = t >> 6, lane = t & 63;
    int g = lane >> 4;      // group 0..3 (one edge per group per sub-iter)
    int lg = lane & 15;     // lane within group (4 features each)
    int n = blockIdx.x * 4 + wid;
    int r0 = rowstart[n], r1 = rowstart[n + 1];

    float4 acc = make_float4(0.f, 0.f, 0.f, 0.f);
    for (int base = r0; base < r1; base += 64) {
        int ii = base + lane;
        int idx = (ii < r1) ? esrc[ii] : N_NODES;   // zero row
        int rem = r1 - base;                        // wave-uniform
#pragma unroll 1
        for (int c = 0; c < 64; c += 16) {          // chunk of 16 edges
            if (c >= rem) break;                    // wave-uniform break
#pragma unroll
            for (int tt = 0; tt < 4; tt++) {        // 4 independent loads
                int j = c + tt * 4 + g;
                int s = __shfl(idx, j);
                const float4* zr = (const float4*)(zin + (size_t)s * H);
                float4 v = zr[lg];
                acc.x += v.x; acc.y += v.y; acc.z += v.z; acc.w += v.w;
            }
        }
    }
    // reduce across the 4 groups (lanes lg, lg+16, lg+32, lg+48)
#pragma unroll
    for (int off = 16; off < 64; off <<= 1) {
        acc.x += __shfl_xor(acc.x, off);
        acc.y += __shfl_xor(acc.y, off);
        acc.z += __shfl_xor(acc.z, off);
        acc.w += __shfl_xor(acc.w, off);
    }
    float inv = 1.0f / fmaxf((float)(r1 - r0), 1.0f);
    if (g == 0) {
        float4 m = make_float4(acc.x * inv, acc.y * inv, acc.z * inv, acc.w * inv);
        ((float4*)smrow[wid])[lg] = m;
    }
    szrow[wid][lane] = zin[(size_t)n * H + lane];
    __syncthreads();   // covers weight staging + smrow/szrow

    float r = b2[lane];
#pragma unroll
    for (int k = 0; k < H; k++) {
        r += smrow[wid][k] * sWl[k * H + lane] + szrow[wid][k] * sWr[k * H + lane];
    }
    out[(size_t)n * H + lane] = r;
}

// ---------------------------------------------------------------------------
extern "C" void kernel_launch(void* const* d_in, const int* in_sizes, int n_in,
                              void* d_out, int out_size, void* d_ws, size_t ws_size,
                              hipStream_t stream) {
    const float* x   = (const float*)d_in[0];
    const int*   ei  = (const int*)d_in[1];   // [2, N_EDGES]
    const float* W1l = (const float*)d_in[2];
    const float* b1  = (const float*)d_in[3];
    const float* W1r = (const float*)d_in[4];
    const float* W2l = (const float*)d_in[5];
    const float* b2  = (const float*)d_in[6];
    const float* W2r = (const float*)d_in[7];
    float* out = (float*)d_out;

    // Workspace layout:
    int*   deg      = (int*)d_ws;                  // 50000
    int*   rowstart = deg + N_NODES;               // 50001
    int*   cursor   = rowstart + N_NODES + 1;      // 50000
    int*   esrc     = cursor + N_NODES;            // 1600000
    int*   blocksum = esrc + N_EDGES;              // 196
    int*   blockoff = blocksum + SCAN_BLOCKS;      // 196 (+pad to align)
    float* z        = (float*)(blockoff + SCAN_BLOCKS + 8);  // (N_NODES+1)*H

    hipMemsetAsync(deg, 0, (size_t)N_NODES * sizeof(int), stream);
    hipMemsetAsync(z + (size_t)N_NODES * H, 0, H * sizeof(float), stream);  // zero row

    // CSR build
    hist_kernel<<<(N_EDGES + 255) / 256, 256, 0, stream>>>(ei, deg);
    scan_local<<<SCAN_BLOCKS, 256, 0, stream>>>(deg, rowstart, blocksum, N_NODES);
    scan_local<<<1, 256, 0, stream>>>(blocksum, blockoff, rowstart + N_NODES, SCAN_BLOCKS);
    scan_add<<<SCAN_BLOCKS, 256, 0, stream>>>(rowstart, cursor, blockoff);
    scatter_kernel<<<(N_EDGES + 255) / 256, 256, 0, stream>>>(ei, cursor, esrc);

    // Fused layers (one wave per node; 50000 = 12500 * 4 exactly)
    layer1_fused<<<N_NODES / 4, 256, 0, stream>>>(x, rowstart, esrc, W1l, b1, W1r, z);
    layer2_fused<<<N_NODES / 4, 256, 0, stream>>>(z, rowstart, esrc, W2l, b2, W2r, out);
}

// Round 4
// 243.711 us; speedup vs baseline: 2.7348x; 1.5617x over previous
//
#include <hip/hip_runtime.h>

#define N_NODES 50000
#define N_EDGES 1600000
#define IN_DIM 6
#define H 64

#define NBUCKET 196            // dst >> 8  (256 nodes per bucket)
#define NBLK 196               // edge chunks
#define EPB 8192               // edges per chunk (196*8192 >= 1.6M)
#define COUNTS_N (NBUCKET * NBLK)            // 38416
#define SCAN2_BLOCKS ((COUNTS_N + 255) / 256)  // 151

// ---------------------------------------------------------------------------
// Pass A1: per-(bucket, block) histogram.  LDS-only atomics.
// counts layout: counts[bucket * NBLK + blk]  (bucket-major for the scan)
// ---------------------------------------------------------------------------
__global__ __launch_bounds__(256) void bin_count(const int* __restrict__ ei,
                                                 int* __restrict__ counts) {
    __shared__ int hist[NBUCKET];
    int t = threadIdx.x;
    for (int i = t; i < NBUCKET; i += 256) hist[i] = 0;
    __syncthreads();
    int e0 = blockIdx.x * EPB;
    int e1 = min(e0 + EPB, N_EDGES);
    for (int e = e0 + t; e < e1; e += 256) {
        int dst = ei[N_EDGES + e];
        atomicAdd(&hist[dst >> 8], 1);
    }
    __syncthreads();
    for (int i = t; i < NBUCKET; i += 256)
        counts[i * NBLK + blockIdx.x] = hist[i];
}

// ---------------------------------------------------------------------------
// Generic per-block exclusive scan; block totals -> sums[b].
// ---------------------------------------------------------------------------
__global__ __launch_bounds__(256) void scan_local(const int* __restrict__ in,
                                                  int* __restrict__ out,
                                                  int* __restrict__ sums,
                                                  int n) {
    __shared__ int wsum[4];
    int t = threadIdx.x, lane = t & 63, w = t >> 6;
    int i = blockIdx.x * 256 + t;
    int v = (i < n) ? in[i] : 0;
    int s = v;
#pragma unroll
    for (int off = 1; off < 64; off <<= 1) {
        int u = __shfl_up(s, off);
        if (lane >= off) s += u;
    }
    if (lane == 63) wsum[w] = s;
    __syncthreads();
    int woff = 0;
    for (int k = 0; k < w; k++) woff += wsum[k];
    if (i < n) out[i] = s - v + woff;
    if (t == 255) sums[blockIdx.x] = woff + s;
}

__global__ void scan_add(int* __restrict__ data,
                         const int* __restrict__ blockoff, int n) {
    int i = blockIdx.x * 256 + threadIdx.x;
    if (i < n) data[i] += blockoff[blockIdx.x];
}

// ---------------------------------------------------------------------------
// Pass A3: scatter packed (src<<16 | dst) into bucket-grouped order.
// LDS cursors; each (block,bucket) run is contiguous (~42 edges).
// ---------------------------------------------------------------------------
__global__ __launch_bounds__(256) void bin_scatter(const int* __restrict__ ei,
                                                   const int* __restrict__ offsets,
                                                   unsigned int* __restrict__ ebin) {
    __shared__ int cur[NBUCKET];
    int t = threadIdx.x;
    for (int i = t; i < NBUCKET; i += 256)
        cur[i] = offsets[i * NBLK + blockIdx.x];
    __syncthreads();
    int e0 = blockIdx.x * EPB;
    int e1 = min(e0 + EPB, N_EDGES);
    for (int e = e0 + t; e < e1; e += 256) {
        int src = ei[e];
        int dst = ei[N_EDGES + e];
        int pos = atomicAdd(&cur[dst >> 8], 1);
        ebin[pos] = ((unsigned int)src << 16) | (unsigned int)dst;
    }
}

// ---------------------------------------------------------------------------
// Pass B: one block per bucket (256 nodes, ~8192 edges).
//  - LDS degree histogram over the bucket's 256 nodes
//  - LDS scan -> rowstart (bucket base = offsets[b*NBLK], free from pass A)
//  - scatter src into esrc within this block's PRIVATE 32 KB region
// ---------------------------------------------------------------------------
__global__ __launch_bounds__(256) void bucket_build(
        const unsigned int* __restrict__ ebin,
        const int* __restrict__ offsets,
        int* __restrict__ rowstart,
        int* __restrict__ esrc) {
    __shared__ int sdeg[256];
    __shared__ int scur[256];
    __shared__ int wsum[4];
    int t = threadIdx.x, lane = t & 63, w = t >> 6;
    int b = blockIdx.x;
    int base = b << 8;
    int nn = min(256, N_NODES - base);
    int bs0 = offsets[b * NBLK];
    int bs1 = (b == NBUCKET - 1) ? N_EDGES : offsets[(b + 1) * NBLK];

    sdeg[t] = 0;
    __syncthreads();
    for (int i = bs0 + t; i < bs1; i += 256) {
        int dl = (int)(ebin[i] & 0xffffu) - base;
        atomicAdd(&sdeg[dl], 1);
    }
    __syncthreads();
    int v = sdeg[t];
    int s = v;
#pragma unroll
    for (int off = 1; off < 64; off <<= 1) {
        int u = __shfl_up(s, off);
        if (lane >= off) s += u;
    }
    if (lane == 63) wsum[w] = s;
    __syncthreads();
    int woff = 0;
    for (int k = 0; k < w; k++) woff += wsum[k];
    int excl = bs0 + s - v + woff;
    if (t < nn) rowstart[base + t] = excl;
    scur[t] = excl;
    if (b == NBUCKET - 1 && t == 0) rowstart[N_NODES] = N_EDGES;
    __syncthreads();
    for (int i = bs0 + t; i < bs1; i += 256) {
        unsigned int p = ebin[i];
        int dl = (int)(p & 0xffffu) - base;
        int pos = atomicAdd(&scur[dl], 1);
        esrc[pos] = (int)(p >> 16);
    }
}

// ---------------------------------------------------------------------------
// Layer 1 fused: per-node neighbor mean of x (6-dim) + linear + relu.
// ---------------------------------------------------------------------------
__global__ __launch_bounds__(256) void layer1_fused(
        const float* __restrict__ x,
        const int* __restrict__ rowstart,
        const int* __restrict__ esrc,
        const float* __restrict__ W1l,
        const float* __restrict__ b1,
        const float* __restrict__ W1r,
        float* __restrict__ z) {
    __shared__ float sWl[IN_DIM * H];
    __shared__ float sWr[IN_DIM * H];
    int t = threadIdx.x;
    for (int i = t; i < IN_DIM * H; i += 256) {
        sWl[i] = W1l[i];
        sWr[i] = W1r[i];
    }
    __syncthreads();

    int wid = t >> 6, lane = t & 63;
    int n = blockIdx.x * 4 + wid;
    int r0 = rowstart[n], r1 = rowstart[n + 1];

    float a0 = 0.f, a1 = 0.f, a2 = 0.f, a3 = 0.f, a4 = 0.f, a5 = 0.f;
    for (int i = r0 + lane; i < r1; i += 64) {
        const float* xs = x + (size_t)esrc[i] * IN_DIM;
        a0 += xs[0]; a1 += xs[1]; a2 += xs[2];
        a3 += xs[3]; a4 += xs[4]; a5 += xs[5];
    }
#pragma unroll
    for (int off = 1; off < 64; off <<= 1) {
        a0 += __shfl_xor(a0, off);
        a1 += __shfl_xor(a1, off);
        a2 += __shfl_xor(a2, off);
        a3 += __shfl_xor(a3, off);
        a4 += __shfl_xor(a4, off);
        a5 += __shfl_xor(a5, off);
    }
    float inv = 1.0f / fmaxf((float)(r1 - r0), 1.0f);
    float m[IN_DIM] = {a0 * inv, a1 * inv, a2 * inv, a3 * inv, a4 * inv, a5 * inv};

    const float* xn = x + (size_t)n * IN_DIM;
    int h = lane;
    float acc = b1[h];
#pragma unroll
    for (int k = 0; k < IN_DIM; k++) {
        acc += m[k] * sWl[k * H + h] + xn[k] * sWr[k * H + h];
    }
    z[(size_t)n * H + h] = fmaxf(acc, 0.0f);
}

// ---------------------------------------------------------------------------
// Layer 2 fused: per-node neighbor mean of z (64-dim) + linear.
// 4 groups of 16 lanes, float4 row reads, 4 loads in flight per lane.
// ---------------------------------------------------------------------------
__global__ __launch_bounds__(256) void layer2_fused(
        const float* __restrict__ zin,
        const int* __restrict__ rowstart,
        const int* __restrict__ esrc,
        const float* __restrict__ W2l,
        const float* __restrict__ b2,
        const float* __restrict__ W2r,
        float* __restrict__ out) {
    __shared__ float sWl[H * H];
    __shared__ float sWr[H * H];
    __shared__ float smrow[4][H];
    __shared__ float szrow[4][H];
    int t = threadIdx.x;
    for (int i = t; i < H * H; i += 256) {
        sWl[i] = W2l[i];
        sWr[i] = W2r[i];
    }

    int wid = t >> 6, lane = t & 63;
    int g = lane >> 4;
    int lg = lane & 15;
    int n = blockIdx.x * 4 + wid;
    int r0 = rowstart[n], r1 = rowstart[n + 1];

    float4 acc = make_float4(0.f, 0.f, 0.f, 0.f);
    for (int base = r0; base < r1; base += 64) {
        int ii = base + lane;
        int idx = (ii < r1) ? esrc[ii] : N_NODES;   // zero row
        int rem = r1 - base;
#pragma unroll 1
        for (int c = 0; c < 64; c += 16) {
            if (c >= rem) break;
#pragma unroll
            for (int tt = 0; tt < 4; tt++) {
                int j = c + tt * 4 + g;
                int s = __shfl(idx, j);
                const float4* zr = (const float4*)(zin + (size_t)s * H);
                float4 v = zr[lg];
                acc.x += v.x; acc.y += v.y; acc.z += v.z; acc.w += v.w;
            }
        }
    }
#pragma unroll
    for (int off = 16; off < 64; off <<= 1) {
        acc.x += __shfl_xor(acc.x, off);
        acc.y += __shfl_xor(acc.y, off);
        acc.z += __shfl_xor(acc.z, off);
        acc.w += __shfl_xor(acc.w, off);
    }
    float inv = 1.0f / fmaxf((float)(r1 - r0), 1.0f);
    if (g == 0) {
        float4 m = make_float4(acc.x * inv, acc.y * inv, acc.z * inv, acc.w * inv);
        ((float4*)smrow[wid])[lg] = m;
    }
    szrow[wid][lane] = zin[(size_t)n * H + lane];
    __syncthreads();

    float r = b2[lane];
#pragma unroll
    for (int k = 0; k < H; k++) {
        r += smrow[wid][k] * sWl[k * H + lane] + szrow[wid][k] * sWr[k * H + lane];
    }
    out[(size_t)n * H + lane] = r;
}

// ---------------------------------------------------------------------------
extern "C" void kernel_launch(void* const* d_in, const int* in_sizes, int n_in,
                              void* d_out, int out_size, void* d_ws, size_t ws_size,
                              hipStream_t stream) {
    const float* x   = (const float*)d_in[0];
    const int*   ei  = (const int*)d_in[1];   // [2, N_EDGES]
    const float* W1l = (const float*)d_in[2];
    const float* b1  = (const float*)d_in[3];
    const float* W1r = (const float*)d_in[4];
    const float* W2l = (const float*)d_in[5];
    const float* b2  = (const float*)d_in[6];
    const float* W2r = (const float*)d_in[7];
    float* out = (float*)d_out;

    // Workspace layout (ints unless noted):
    int* counts   = (int*)d_ws;                     // 38416
    int* offsets  = counts + COUNTS_N;              // 38416
    int* sums     = offsets + COUNTS_N;             // 151 (+ pad)
    int* blockoff = sums + 256;                     // 151 (+ pad)
    int* dummy    = blockoff + 256;                 // 8
    int* rowstart = dummy + 8;                      // 50001 (+ pad to even)
    unsigned int* ebin = (unsigned int*)(rowstart + 50008);  // 1600000
    int* esrc     = (int*)(ebin + N_EDGES);         // 1600000
    float* z      = (float*)(esrc + N_EDGES);       // (N_NODES+1)*H floats

    // zero row of z for layer2's out-of-range clamp
    hipMemsetAsync(z + (size_t)N_NODES * H, 0, H * sizeof(float), stream);

    // CSR build via bucketed counting sort (no global atomics, private regions)
    bin_count<<<NBLK, 256, 0, stream>>>(ei, counts);
    scan_local<<<SCAN2_BLOCKS, 256, 0, stream>>>(counts, offsets, sums, COUNTS_N);
    scan_local<<<1, 256, 0, stream>>>(sums, blockoff, dummy, SCAN2_BLOCKS);
    scan_add<<<SCAN2_BLOCKS, 256, 0, stream>>>(offsets, blockoff, COUNTS_N);
    bin_scatter<<<NBLK, 256, 0, stream>>>(ei, offsets, ebin);
    bucket_build<<<NBUCKET, 256, 0, stream>>>(ebin, offsets, rowstart, esrc);

    // Fused layers (one wave per node; 50000 = 12500 * 4 exactly)
    layer1_fused<<<N_NODES / 4, 256, 0, stream>>>(x, rowstart, esrc, W1l, b1, W1r, z);
    layer2_fused<<<N_NODES / 4, 256, 0, stream>>>(z, rowstart, esrc, W2l, b2, W2r, out);
}

// Round 5
// 214.558 us; speedup vs baseline: 3.1064x; 1.1359x over previous
//
#include <hip/hip_runtime.h>

#define N_NODES 50000
#define N_EDGES 1600000
#define IN_DIM 6
#define H 64

#define NBUCKET 196            // dst >> 8  (256 nodes per bucket)
#define NBLK 196               // edge chunks
#define EPB 8192               // edges per chunk (196*8192 >= 1.6M)
#define COUNTS_N (NBUCKET * NBLK)   // 38416
#define BCAP 10240             // bucket edge capacity (mean 8192, sd ~90)

// bf16 helpers (storage-only; all math in fp32)
__device__ __forceinline__ float bf2f(unsigned short u) {
    return __uint_as_float(((unsigned int)u) << 16);
}
__device__ __forceinline__ unsigned short f2bf(float f) {
    unsigned int u = __float_as_uint(f);
    u += 0x7fffu + ((u >> 16) & 1u);   // round-to-nearest-even
    return (unsigned short)(u >> 16);
}

// ---------------------------------------------------------------------------
// Pass A1: per-(bucket, chunk) histogram.  LDS atomics only; int4 edge reads.
// counts layout: counts[bucket * NBLK + blk] (bucket-major for the scan).
// ---------------------------------------------------------------------------
__global__ __launch_bounds__(256) void bin_count(const int* __restrict__ ei,
                                                 int* __restrict__ counts) {
    __shared__ int hist[NBUCKET];
    int t = threadIdx.x;
    for (int i = t; i < NBUCKET; i += 256) hist[i] = 0;
    __syncthreads();
    int e0 = blockIdx.x * EPB;
    int cnt = min(EPB, N_EDGES - e0);          // always a multiple of 4
    const int4* d4 = (const int4*)(ei + N_EDGES + e0);
    for (int k = t; k * 4 < cnt; k += 256) {
        int4 d = d4[k];
        atomicAdd(&hist[d.x >> 8], 1);
        atomicAdd(&hist[d.y >> 8], 1);
        atomicAdd(&hist[d.z >> 8], 1);
        atomicAdd(&hist[d.w >> 8], 1);
    }
    __syncthreads();
    for (int i = t; i < NBUCKET; i += 256)
        counts[i * NBLK + blockIdx.x] = hist[i];
}

// ---------------------------------------------------------------------------
// Single-block pipelined exclusive scan of in[n] -> out[0..n]  (out[n]=total).
// 1024 threads, 16 waves; next chunk prefetched while current is scanned.
// ---------------------------------------------------------------------------
__global__ __launch_bounds__(1024) void scan_full(const int* __restrict__ in,
                                                  int* __restrict__ out, int n) {
    __shared__ int wsum[16];
    __shared__ int woff[16];
    __shared__ int s_carry;
    int t = threadIdx.x, lane = t & 63, w = t >> 6;
    if (t == 0) s_carry = 0;
    int vnext = (t < n) ? in[t] : 0;
    __syncthreads();
    for (int base = 0; base < n; base += 1024) {
        int i = base + t;
        int v = vnext;
        int inext = i + 1024;
        vnext = (inext < n) ? in[inext] : 0;   // prefetch next chunk
        int s = v;
#pragma unroll
        for (int off = 1; off < 64; off <<= 1) {
            int u = __shfl_up(s, off);
            if (lane >= off) s += u;
        }
        if (lane == 63) wsum[w] = s;
        __syncthreads();
        if (t == 0) {
            int acc = 0;
#pragma unroll
            for (int k = 0; k < 16; k++) { woff[k] = acc; acc += wsum[k]; }
            wsum[0] = acc;                      // chunk total
        }
        __syncthreads();
        if (i < n) out[i] = s_carry + woff[w] + s - v;
        __syncthreads();
        if (t == 0) s_carry += wsum[0];
        __syncthreads();
    }
    if (t == 0) out[n] = s_carry;
}

// ---------------------------------------------------------------------------
// Pass A3: scatter packed (src<<16 | dst) into bucket-grouped order.
// LDS cursors; int4 edge reads.
// ---------------------------------------------------------------------------
__global__ __launch_bounds__(256) void bin_scatter(const int* __restrict__ ei,
                                                   const int* __restrict__ offsets,
                                                   unsigned int* __restrict__ ebin) {
    __shared__ int cur[NBUCKET];
    int t = threadIdx.x;
    for (int i = t; i < NBUCKET; i += 256)
        cur[i] = offsets[i * NBLK + blockIdx.x];
    __syncthreads();
    int e0 = blockIdx.x * EPB;
    int cnt = min(EPB, N_EDGES - e0);
    const int4* s4p = (const int4*)(ei + e0);
    const int4* d4p = (const int4*)(ei + N_EDGES + e0);
    for (int k = t; k * 4 < cnt; k += 256) {
        int4 sv = s4p[k];
        int4 dv = d4p[k];
        int pos;
        pos = atomicAdd(&cur[dv.x >> 8], 1); ebin[pos] = ((unsigned)sv.x << 16) | (unsigned)dv.x;
        pos = atomicAdd(&cur[dv.y >> 8], 1); ebin[pos] = ((unsigned)sv.y << 16) | (unsigned)dv.y;
        pos = atomicAdd(&cur[dv.z >> 8], 1); ebin[pos] = ((unsigned)sv.z << 16) | (unsigned)dv.z;
        pos = atomicAdd(&cur[dv.w >> 8], 1); ebin[pos] = ((unsigned)sv.w << 16) | (unsigned)dv.w;
    }
}

// ---------------------------------------------------------------------------
// Pass B: one block per bucket, fully LDS-resident.
// Read bucket edges once into LDS -> hist -> scan -> in-LDS scatter ->
// coalesced ushort esrc write.  No global scatters.
// ---------------------------------------------------------------------------
__global__ __launch_bounds__(256) void bucket_build(
        const unsigned int* __restrict__ ebin,
        const int* __restrict__ offsets,
        int* __restrict__ rowstart,
        unsigned short* __restrict__ esrc) {
    __shared__ int raw[BCAP];
    __shared__ unsigned short ssrc[BCAP];
    __shared__ int sdeg[256];
    __shared__ int scur[256];
    __shared__ int wsum[4];
    int t = threadIdx.x, lane = t & 63, w = t >> 6;
    int b = blockIdx.x;
    int base = b << 8;
    int nn = min(256, N_NODES - base);
    int bs0 = offsets[b * NBLK];
    int bs1 = (b == NBUCKET - 1) ? N_EDGES : offsets[(b + 1) * NBLK];
    int cnt = min(bs1 - bs0, BCAP);   // BCAP is ~20 sd above the mean; safe

    sdeg[t] = 0;
    for (int i = t; i < cnt; i += 256) raw[i] = (int)ebin[bs0 + i];
    __syncthreads();
    for (int i = t; i < cnt; i += 256) atomicAdd(&sdeg[raw[i] & 0xff], 1);
    __syncthreads();
    int v = sdeg[t], s = v;
#pragma unroll
    for (int off = 1; off < 64; off <<= 1) {
        int u = __shfl_up(s, off);
        if (lane >= off) s += u;
    }
    if (lane == 63) wsum[w] = s;
    __syncthreads();
    int woff2 = 0;
    for (int k = 0; k < w; k++) woff2 += wsum[k];
    int excl = s - v + woff2;                 // bucket-local exclusive prefix
    if (t < nn) rowstart[base + t] = bs0 + excl;
    scur[t] = excl;
    if (b == NBUCKET - 1 && t == 0) rowstart[N_NODES] = N_EDGES;
    __syncthreads();
    for (int i = t; i < cnt; i += 256) {
        int p = raw[i];
        int pos = atomicAdd(&scur[p & 0xff], 1);
        ssrc[pos] = (unsigned short)(((unsigned)p) >> 16);
    }
    __syncthreads();
    for (int i = t; i < cnt; i += 256)        // coalesced write-out
        esrc[bs0 + i] = ssrc[i];
}

// ---------------------------------------------------------------------------
// Layer 1 fused: neighbor mean of x (6-dim) + linear + relu -> bf16 z.
// One wave per node; 2 lanes per edge (3 floats each) so all 64 lanes are
// active at mean degree 32.  Extra block (grid = 12501) zeroes z's dummy row.
// ---------------------------------------------------------------------------
__global__ __launch_bounds__(256) void layer1_fused(
        const float* __restrict__ x,
        const int* __restrict__ rowstart,
        const unsigned short* __restrict__ esrc,
        const float* __restrict__ W1l,
        const float* __restrict__ b1,
        const float* __restrict__ W1r,
        unsigned short* __restrict__ z) {
    __shared__ float sWl[IN_DIM * H];
    __shared__ float sWr[IN_DIM * H];
    int t = threadIdx.x;
    for (int i = t; i < IN_DIM * H; i += 256) {
        sWl[i] = W1l[i];
        sWr[i] = W1r[i];
    }
    __syncthreads();

    int wid = t >> 6, lane = t & 63;
    int n = blockIdx.x * 4 + wid;
    if (n >= N_NODES) {                        // zero-row block (blockIdx 12500)
        if (t < H) z[(size_t)N_NODES * H + t] = 0;
        return;
    }
    int r0 = rowstart[n], r1 = rowstart[n + 1];
    int nh = 2 * (r1 - r0);                    // edge-halves
    int half = lane & 1;                       // parity constant per lane
    float a0 = 0.f, a1 = 0.f, a2 = 0.f;
    for (int hh = lane; hh < nh; hh += 64) {
        int src = esrc[r0 + (hh >> 1)];
        const float* xs = x + (size_t)src * IN_DIM + half * 3;
        a0 += xs[0]; a1 += xs[1]; a2 += xs[2];
    }
    // reduce within parity class (offsets 2..32 keep parities separate)
#pragma unroll
    for (int off = 2; off < 64; off <<= 1) {
        a0 += __shfl_xor(a0, off);
        a1 += __shfl_xor(a1, off);
        a2 += __shfl_xor(a2, off);
    }
    float m[IN_DIM];
    m[0] = __shfl(a0, 0); m[1] = __shfl(a1, 0); m[2] = __shfl(a2, 0);
    m[3] = __shfl(a0, 1); m[4] = __shfl(a1, 1); m[5] = __shfl(a2, 1);
    float inv = 1.0f / fmaxf((float)(r1 - r0), 1.0f);

    const float* xn = x + (size_t)n * IN_DIM;
    float acc = b1[lane];
#pragma unroll
    for (int k = 0; k < IN_DIM; k++) {
        acc += m[k] * inv * sWl[k * H + lane] + xn[k] * sWr[k * H + lane];
    }
    z[(size_t)n * H + lane] = f2bf(fmaxf(acc, 0.0f));
}

// ---------------------------------------------------------------------------
// Layer 2 fused: neighbor mean of bf16 z (64-dim) + linear -> fp32 out.
// 512 threads = 8 waves sharing the 32KB weight tile (LDS 36KB -> 4 blk/CU
// = 32 waves/CU).  Gather: 4 groups of 16 lanes, ushort4 (8B) row reads,
// 4 independent loads in flight per lane.
// ---------------------------------------------------------------------------
__global__ __launch_bounds__(512) void layer2_fused(
        const unsigned short* __restrict__ zin,
        const int* __restrict__ rowstart,
        const unsigned short* __restrict__ esrc,
        const float* __restrict__ W2l,
        const float* __restrict__ b2,
        const float* __restrict__ W2r,
        float* __restrict__ out) {
    __shared__ float sWl[H * H];
    __shared__ float sWr[H * H];
    __shared__ float smrow[8][H];
    __shared__ float szrow[8][H];
    int t = threadIdx.x;
    for (int i = t; i < H * H; i += 512) {
        sWl[i] = W2l[i];
        sWr[i] = W2r[i];
    }

    int wid = t >> 6, lane = t & 63;
    int g = lane >> 4;
    int lg = lane & 15;
    int n = blockIdx.x * 8 + wid;
    int r0 = rowstart[n], r1 = rowstart[n + 1];

    float4 acc = make_float4(0.f, 0.f, 0.f, 0.f);
    for (int base = r0; base < r1; base += 64) {
        int ii = base + lane;
        int idx = (ii < r1) ? (int)esrc[ii] : N_NODES;   // zero row
        int rem = r1 - base;                             // wave-uniform
#pragma unroll 1
        for (int c = 0; c < 64; c += 16) {
            if (c >= rem) break;                         // wave-uniform
#pragma unroll
            for (int tt = 0; tt < 4; tt++) {
                int j = c + tt * 4 + g;
                int s = __shfl(idx, j);
                const ushort4* zr = (const ushort4*)(zin + (size_t)s * H);
                ushort4 v = zr[lg];
                acc.x += bf2f(v.x); acc.y += bf2f(v.y);
                acc.z += bf2f(v.z); acc.w += bf2f(v.w);
            }
        }
    }
#pragma unroll
    for (int off = 16; off < 64; off <<= 1) {
        acc.x += __shfl_xor(acc.x, off);
        acc.y += __shfl_xor(acc.y, off);
        acc.z += __shfl_xor(acc.z, off);
        acc.w += __shfl_xor(acc.w, off);
    }
    float inv = 1.0f / fmaxf((float)(r1 - r0), 1.0f);
    if (g == 0) {
        ((float4*)smrow[wid])[lg] =
            make_float4(acc.x * inv, acc.y * inv, acc.z * inv, acc.w * inv);
    }
    szrow[wid][lane] = bf2f(zin[(size_t)n * H + lane]);
    __syncthreads();   // covers weight staging + smrow/szrow; all threads reach

    float r = b2[lane];
#pragma unroll
    for (int k = 0; k < H; k++) {
        r += smrow[wid][k] * sWl[k * H + lane] + szrow[wid][k] * sWr[k * H + lane];
    }
    out[(size_t)n * H + lane] = r;
}

// ---------------------------------------------------------------------------
extern "C" void kernel_launch(void* const* d_in, const int* in_sizes, int n_in,
                              void* d_out, int out_size, void* d_ws, size_t ws_size,
                              hipStream_t stream) {
    const float* x   = (const float*)d_in[0];
    const int*   ei  = (const int*)d_in[1];   // [2, N_EDGES]
    const float* W1l = (const float*)d_in[2];
    const float* b1  = (const float*)d_in[3];
    const float* W1r = (const float*)d_in[4];
    const float* W2l = (const float*)d_in[5];
    const float* b2  = (const float*)d_in[6];
    const float* W2r = (const float*)d_in[7];
    float* out = (float*)d_out;

    // Workspace layout (all offsets keep 16B alignment for ebin/z):
    int* counts   = (int*)d_ws;                          // 38416
    int* offsets  = counts + COUNTS_N;                   // 38416 + 8
    int* rowstart = offsets + COUNTS_N + 8;              // 50001 (+pad to 50008)
    unsigned int*   ebin = (unsigned int*)(rowstart + 50008);   // 1600000
    unsigned short* esrc = (unsigned short*)(ebin + N_EDGES);   // 1600000 u16
    unsigned short* z    = esrc + N_EDGES;               // (N_NODES+1)*H bf16

    // CSR build via bucketed counting sort (LDS atomics only)
    bin_count<<<NBLK, 256, 0, stream>>>(ei, counts);
    scan_full<<<1, 1024, 0, stream>>>(counts, offsets, COUNTS_N);
    bin_scatter<<<NBLK, 256, 0, stream>>>(ei, offsets, ebin);
    bucket_build<<<NBUCKET, 256, 0, stream>>>(ebin, offsets, rowstart, esrc);

    // Fused layers (+1 block in layer1 zeroes the dummy z row)
    layer1_fused<<<N_NODES / 4 + 1, 256, 0, stream>>>(x, rowstart, esrc,
                                                      W1l, b1, W1r, z);
    layer2_fused<<<N_NODES / 8, 512, 0, stream>>>(z, rowstart, esrc,
                                                  W2l, b2, W2r, out);
}

// Round 6
// 204.144 us; speedup vs baseline: 3.2649x; 1.0510x over previous
//
#include <hip/hip_runtime.h>

#define N_NODES 50000
#define N_EDGES 1600000
#define IN_DIM 6
#define H 64

#define NBUCKET 196            // dst >> 8  (256 nodes per bucket)
#define NBLK 196               // edge chunks
#define EPB 8192               // edges per chunk (196*8192 >= 1.6M)
#define COUNTS_N (NBUCKET * NBLK)   // 38416
#define BCAP 10240             // bucket edge capacity (mean 8192, sd ~90)

#define L2PAD 72               // padded LDS row stride (bf16) = 144B: 2-way bank alias (free)

// bf16 helpers (storage-only; all math in fp32)
__device__ __forceinline__ float bf2f(unsigned short u) {
    return __uint_as_float(((unsigned int)u) << 16);
}
__device__ __forceinline__ unsigned short f2bf(float f) {
    unsigned int u = __float_as_uint(f);
    u += 0x7fffu + ((u >> 16) & 1u);   // round-to-nearest-even
    return (unsigned short)(u >> 16);
}

// ---------------------------------------------------------------------------
// Pass A1: per-(bucket, chunk) histogram.  LDS atomics only; int4 edge reads.
// ---------------------------------------------------------------------------
__global__ __launch_bounds__(256) void bin_count(const int* __restrict__ ei,
                                                 int* __restrict__ counts) {
    __shared__ int hist[NBUCKET];
    int t = threadIdx.x;
    for (int i = t; i < NBUCKET; i += 256) hist[i] = 0;
    __syncthreads();
    int e0 = blockIdx.x * EPB;
    int cnt = min(EPB, N_EDGES - e0);          // always a multiple of 4
    const int4* d4 = (const int4*)(ei + N_EDGES + e0);
    for (int k = t; k * 4 < cnt; k += 256) {
        int4 d = d4[k];
        atomicAdd(&hist[d.x >> 8], 1);
        atomicAdd(&hist[d.y >> 8], 1);
        atomicAdd(&hist[d.z >> 8], 1);
        atomicAdd(&hist[d.w >> 8], 1);
    }
    __syncthreads();
    for (int i = t; i < NBUCKET; i += 256)
        counts[i * NBLK + blockIdx.x] = hist[i];
}

// ---------------------------------------------------------------------------
// Single-block pipelined exclusive scan of in[n] -> out[0..n]  (out[n]=total).
// ---------------------------------------------------------------------------
__global__ __launch_bounds__(1024) void scan_full(const int* __restrict__ in,
                                                  int* __restrict__ out, int n) {
    __shared__ int wsum[16];
    __shared__ int woff[16];
    __shared__ int s_carry;
    int t = threadIdx.x, lane = t & 63, w = t >> 6;
    if (t == 0) s_carry = 0;
    int vnext = (t < n) ? in[t] : 0;
    __syncthreads();
    for (int base = 0; base < n; base += 1024) {
        int i = base + t;
        int v = vnext;
        int inext = i + 1024;
        vnext = (inext < n) ? in[inext] : 0;   // prefetch next chunk
        int s = v;
#pragma unroll
        for (int off = 1; off < 64; off <<= 1) {
            int u = __shfl_up(s, off);
            if (lane >= off) s += u;
        }
        if (lane == 63) wsum[w] = s;
        __syncthreads();
        if (t == 0) {
            int acc = 0;
#pragma unroll
            for (int k = 0; k < 16; k++) { woff[k] = acc; acc += wsum[k]; }
            wsum[0] = acc;                      // chunk total
        }
        __syncthreads();
        if (i < n) out[i] = s_carry + woff[w] + s - v;
        __syncthreads();
        if (t == 0) s_carry += wsum[0];
        __syncthreads();
    }
    if (t == 0) out[n] = s_carry;
}

// ---------------------------------------------------------------------------
// Pass A3: scatter packed (src<<16 | dst) into bucket-grouped order.
// ---------------------------------------------------------------------------
__global__ __launch_bounds__(256) void bin_scatter(const int* __restrict__ ei,
                                                   const int* __restrict__ offsets,
                                                   unsigned int* __restrict__ ebin) {
    __shared__ int cur[NBUCKET];
    int t = threadIdx.x;
    for (int i = t; i < NBUCKET; i += 256)
        cur[i] = offsets[i * NBLK + blockIdx.x];
    __syncthreads();
    int e0 = blockIdx.x * EPB;
    int cnt = min(EPB, N_EDGES - e0);
    const int4* s4p = (const int4*)(ei + e0);
    const int4* d4p = (const int4*)(ei + N_EDGES + e0);
    for (int k = t; k * 4 < cnt; k += 256) {
        int4 sv = s4p[k];
        int4 dv = d4p[k];
        int pos;
        pos = atomicAdd(&cur[dv.x >> 8], 1); ebin[pos] = ((unsigned)sv.x << 16) | (unsigned)dv.x;
        pos = atomicAdd(&cur[dv.y >> 8], 1); ebin[pos] = ((unsigned)sv.y << 16) | (unsigned)dv.y;
        pos = atomicAdd(&cur[dv.z >> 8], 1); ebin[pos] = ((unsigned)sv.z << 16) | (unsigned)dv.z;
        pos = atomicAdd(&cur[dv.w >> 8], 1); ebin[pos] = ((unsigned)sv.w << 16) | (unsigned)dv.w;
    }
}

// ---------------------------------------------------------------------------
// Pass B: one block per bucket, fully LDS-resident counting sort.
// ---------------------------------------------------------------------------
__global__ __launch_bounds__(256) void bucket_build(
        const unsigned int* __restrict__ ebin,
        const int* __restrict__ offsets,
        int* __restrict__ rowstart,
        unsigned short* __restrict__ esrc) {
    __shared__ int raw[BCAP];
    __shared__ unsigned short ssrc[BCAP];
    __shared__ int sdeg[256];
    __shared__ int scur[256];
    __shared__ int wsum[4];
    int t = threadIdx.x, lane = t & 63, w = t >> 6;
    int b = blockIdx.x;
    int base = b << 8;
    int nn = min(256, N_NODES - base);
    int bs0 = offsets[b * NBLK];
    int bs1 = (b == NBUCKET - 1) ? N_EDGES : offsets[(b + 1) * NBLK];
    int cnt = min(bs1 - bs0, BCAP);

    sdeg[t] = 0;
    for (int i = t; i < cnt; i += 256) raw[i] = (int)ebin[bs0 + i];
    __syncthreads();
    for (int i = t; i < cnt; i += 256) atomicAdd(&sdeg[raw[i] & 0xff], 1);
    __syncthreads();
    int v = sdeg[t], s = v;
#pragma unroll
    for (int off = 1; off < 64; off <<= 1) {
        int u = __shfl_up(s, off);
        if (lane >= off) s += u;
    }
    if (lane == 63) wsum[w] = s;
    __syncthreads();
    int woff2 = 0;
    for (int k = 0; k < w; k++) woff2 += wsum[k];
    int excl = s - v + woff2;                 // bucket-local exclusive prefix
    if (t < nn) rowstart[base + t] = bs0 + excl;
    scur[t] = excl;
    if (b == NBUCKET - 1 && t == 0) rowstart[N_NODES] = N_EDGES;
    __syncthreads();
    for (int i = t; i < cnt; i += 256) {
        int p = raw[i];
        int pos = atomicAdd(&scur[p & 0xff], 1);
        ssrc[pos] = (unsigned short)(((unsigned)p) >> 16);
    }
    __syncthreads();
    for (int i = t; i < cnt; i += 256)        // coalesced write-out
        esrc[bs0 + i] = ssrc[i];
}

// ---------------------------------------------------------------------------
// Layer 1 fused: neighbor mean of x (6-dim) + linear + relu -> bf16 z.
// ---------------------------------------------------------------------------
__global__ __launch_bounds__(256) void layer1_fused(
        const float* __restrict__ x,
        const int* __restrict__ rowstart,
        const unsigned short* __restrict__ esrc,
        const float* __restrict__ W1l,
        const float* __restrict__ b1,
        const float* __restrict__ W1r,
        unsigned short* __restrict__ z) {
    __shared__ float sWl[IN_DIM * H];
    __shared__ float sWr[IN_DIM * H];
    int t = threadIdx.x;
    for (int i = t; i < IN_DIM * H; i += 256) {
        sWl[i] = W1l[i];
        sWr[i] = W1r[i];
    }
    __syncthreads();

    int wid = t >> 6, lane = t & 63;
    int n = blockIdx.x * 4 + wid;
    if (n >= N_NODES) {                        // zero-row block (blockIdx 12500)
        if (t < H) z[(size_t)N_NODES * H + t] = 0;
        return;
    }
    int r0 = rowstart[n], r1 = rowstart[n + 1];
    int nh = 2 * (r1 - r0);                    // edge-halves
    int half = lane & 1;
    float a0 = 0.f, a1 = 0.f, a2 = 0.f;
    for (int hh = lane; hh < nh; hh += 64) {
        int src = esrc[r0 + (hh >> 1)];
        const float* xs = x + (size_t)src * IN_DIM + half * 3;
        a0 += xs[0]; a1 += xs[1]; a2 += xs[2];
    }
#pragma unroll
    for (int off = 2; off < 64; off <<= 1) {
        a0 += __shfl_xor(a0, off);
        a1 += __shfl_xor(a1, off);
        a2 += __shfl_xor(a2, off);
    }
    float m[IN_DIM];
    m[0] = __shfl(a0, 0); m[1] = __shfl(a1, 0); m[2] = __shfl(a2, 0);
    m[3] = __shfl(a0, 1); m[4] = __shfl(a1, 1); m[5] = __shfl(a2, 1);
    float inv = 1.0f / fmaxf((float)(r1 - r0), 1.0f);

    const float* xn = x + (size_t)n * IN_DIM;
    float acc = b1[lane];
#pragma unroll
    for (int k = 0; k < IN_DIM; k++) {
        acc += m[k] * inv * sWl[k * H + lane] + xn[k] * sWr[k * H + lane];
    }
    z[(size_t)n * H + lane] = f2bf(fmaxf(acc, 0.0f));
}

// ---------------------------------------------------------------------------
// Layer 2, MFMA epilogue.  Block = 256 thr / 4 waves / 64 nodes.
// Phase 1 (gather): wave w aggregates nodes [16w,16w+16) with the proven
//   4-group ushort4 pattern; writes bf16 mean & z rows to LDS (stride 144B).
// Phase 2 (MFMA): out[16x64 tile] = smean @ W2l + sz @ W2r + b2 via
//   16 x mfma_f32_16x16x32_bf16 per wave.  Weights staged transposed (bf16)
//   so B-frags are contiguous ds_read_b128.
// Layouts (verified, m89/m91): A[m=lane&15][k=quad*8+j];
//   B[n=lane&15][k=quad*8+j] (from W^T rows); C/D col=lane&15, row=quad*4+reg.
// ---------------------------------------------------------------------------
__global__ __launch_bounds__(256) void layer2_mfma(
        const unsigned short* __restrict__ zin,
        const int* __restrict__ rowstart,
        const unsigned short* __restrict__ esrc,
        const float* __restrict__ W2l,
        const float* __restrict__ b2,
        const float* __restrict__ W2r,
        float* __restrict__ out) {
    typedef short bf16x8 __attribute__((ext_vector_type(8)));
    typedef float f32x4 __attribute__((ext_vector_type(4)));
    __shared__ __attribute__((aligned(16))) unsigned short smean[64 * L2PAD];
    __shared__ __attribute__((aligned(16))) unsigned short szl[64 * L2PAD];
    __shared__ __attribute__((aligned(16))) unsigned short sWl[64 * L2PAD];
    __shared__ __attribute__((aligned(16))) unsigned short sWr[64 * L2PAD];
    __shared__ float sb2[H];

    int t = threadIdx.x;
    // stage weights: sW*[n][k] = bf16(W[k*H+n])  (transposed)
    for (int i = t; i < H * H; i += 256) {
        int k = i >> 6, n = i & 63;
        sWl[n * L2PAD + k] = f2bf(W2l[i]);
        sWr[n * L2PAD + k] = f2bf(W2r[i]);
    }
    if (t < H) sb2[t] = b2[t];

    int w = t >> 6, lane = t & 63;
    int g = lane >> 4, lg = lane & 15;
    int n0 = blockIdx.x * 64;

    // ---- gather phase ----
    for (int nl = 0; nl < 16; nl++) {
        int ln = w * 16 + nl;
        int n = n0 + ln;
        int r0 = 0, r1 = 0;
        if (n < N_NODES) { r0 = rowstart[n]; r1 = rowstart[n + 1]; }
        float4 acc = make_float4(0.f, 0.f, 0.f, 0.f);
        for (int base = r0; base < r1; base += 64) {
            int ii = base + lane;
            int idx = (ii < r1) ? (int)esrc[ii] : N_NODES;   // zero row
            int rem = r1 - base;                             // wave-uniform
#pragma unroll 1
            for (int c = 0; c < 64; c += 16) {
                if (c >= rem) break;                         // wave-uniform
#pragma unroll
                for (int tt = 0; tt < 4; tt++) {
                    int j = c + tt * 4 + g;
                    int s = __shfl(idx, j);
                    const ushort4* zr = (const ushort4*)(zin + (size_t)s * H);
                    ushort4 v = zr[lg];
                    acc.x += bf2f(v.x); acc.y += bf2f(v.y);
                    acc.z += bf2f(v.z); acc.w += bf2f(v.w);
                }
            }
        }
#pragma unroll
        for (int off = 16; off < 64; off <<= 1) {
            acc.x += __shfl_xor(acc.x, off);
            acc.y += __shfl_xor(acc.y, off);
            acc.z += __shfl_xor(acc.z, off);
            acc.w += __shfl_xor(acc.w, off);
        }
        float inv = 1.0f / fmaxf((float)(r1 - r0), 1.0f);
        if (g == 0) {
            ushort4 mb;
            mb.x = f2bf(acc.x * inv); mb.y = f2bf(acc.y * inv);
            mb.z = f2bf(acc.z * inv); mb.w = f2bf(acc.w * inv);
            *(ushort4*)&smean[ln * L2PAD + lg * 4] = mb;
        }
        int nz = (n < N_NODES) ? n : N_NODES;                // zero row for pad
        szl[ln * L2PAD + lane] = zin[(size_t)nz * H + lane];
    }
    __syncthreads();

    // ---- MFMA phase: wave w -> output rows [16w, 16w+16) ----
    f32x4 acc[4] = {{0,0,0,0},{0,0,0,0},{0,0,0,0},{0,0,0,0}};
#pragma unroll
    for (int ks = 0; ks < 2; ks++) {
        int ko = ks * 32 + g * 8;
        bf16x8 aM = *(const bf16x8*)&smean[(w * 16 + lg) * L2PAD + ko];
        bf16x8 aZ = *(const bf16x8*)&szl[(w * 16 + lg) * L2PAD + ko];
#pragma unroll
        for (int tc = 0; tc < 4; tc++) {
            bf16x8 bL = *(const bf16x8*)&sWl[(tc * 16 + lg) * L2PAD + ko];
            bf16x8 bR = *(const bf16x8*)&sWr[(tc * 16 + lg) * L2PAD + ko];
            acc[tc] = __builtin_amdgcn_mfma_f32_16x16x32_bf16(aM, bL, acc[tc], 0, 0, 0);
            acc[tc] = __builtin_amdgcn_mfma_f32_16x16x32_bf16(aZ, bR, acc[tc], 0, 0, 0);
        }
    }
#pragma unroll
    for (int tc = 0; tc < 4; tc++) {
        float bias = sb2[tc * 16 + lg];
#pragma unroll
        for (int r = 0; r < 4; r++) {
            int node = n0 + w * 16 + g * 4 + r;
            if (node < N_NODES)
                out[(size_t)node * H + tc * 16 + lg] = acc[tc][r] + bias;
        }
    }
}

// ---------------------------------------------------------------------------
extern "C" void kernel_launch(void* const* d_in, const int* in_sizes, int n_in,
                              void* d_out, int out_size, void* d_ws, size_t ws_size,
                              hipStream_t stream) {
    const float* x   = (const float*)d_in[0];
    const int*   ei  = (const int*)d_in[1];   // [2, N_EDGES]
    const float* W1l = (const float*)d_in[2];
    const float* b1  = (const float*)d_in[3];
    const float* W1r = (const float*)d_in[4];
    const float* W2l = (const float*)d_in[5];
    const float* b2  = (const float*)d_in[6];
    const float* W2r = (const float*)d_in[7];
    float* out = (float*)d_out;

    // Workspace layout (keeps 16B alignment for ebin/esrc/z):
    int* counts   = (int*)d_ws;                          // 38416
    int* offsets  = counts + COUNTS_N;                   // 38416 + 8
    int* rowstart = offsets + COUNTS_N + 8;              // 50001 (+pad to 50008)
    unsigned int*   ebin = (unsigned int*)(rowstart + 50008);   // 1600000
    unsigned short* esrc = (unsigned short*)(ebin + N_EDGES);   // 1600000 u16
    unsigned short* z    = esrc + N_EDGES;               // (N_NODES+1)*H bf16

    // CSR build via bucketed counting sort (LDS atomics only)
    bin_count<<<NBLK, 256, 0, stream>>>(ei, counts);
    scan_full<<<1, 1024, 0, stream>>>(counts, offsets, COUNTS_N);
    bin_scatter<<<NBLK, 256, 0, stream>>>(ei, offsets, ebin);
    bucket_build<<<NBUCKET, 256, 0, stream>>>(ebin, offsets, rowstart, esrc);

    // Fused layers (+1 block in layer1 zeroes the dummy z row)
    layer1_fused<<<N_NODES / 4 + 1, 256, 0, stream>>>(x, rowstart, esrc,
                                                      W1l, b1, W1r, z);
    layer2_mfma<<<(N_NODES + 63) / 64, 256, 0, stream>>>(z, rowstart, esrc,
                                                         W2l, b2, W2r, out);
}

// Round 7
// 197.461 us; speedup vs baseline: 3.3754x; 1.0338x over previous
//
#include <hip/hip_runtime.h>

#define N_NODES 50000
#define N_EDGES 1600000
#define IN_DIM 6
#define H 64

#define NBUCKET 196            // dst >> 8  (256 nodes per bucket)
#define NBLK 196               // edge chunks
#define EPB 8192               // edges per chunk (196*8192 >= 1.6M)
#define COUNTS_N (NBUCKET * NBLK)   // 38416
#define BCAP 10240             // bucket edge capacity (mean 8192, sd ~90)

#define L2PAD 72               // padded LDS row stride (bf16) = 144B

// bf16 helpers (storage-only; all math in fp32)
__device__ __forceinline__ float bf2f(unsigned short u) {
    return __uint_as_float(((unsigned int)u) << 16);
}
__device__ __forceinline__ unsigned short f2bf(float f) {
    unsigned int u = __float_as_uint(f);
    u += 0x7fffu + ((u >> 16) & 1u);   // round-to-nearest-even
    return (unsigned short)(u >> 16);
}

// ---------------------------------------------------------------------------
// Pass A1: per-(bucket, chunk) histogram.  LDS atomics only; int4 edge reads.
// ---------------------------------------------------------------------------
__global__ __launch_bounds__(256) void bin_count(const int* __restrict__ ei,
                                                 int* __restrict__ counts) {
    __shared__ int hist[NBUCKET];
    int t = threadIdx.x;
    for (int i = t; i < NBUCKET; i += 256) hist[i] = 0;
    __syncthreads();
    int e0 = blockIdx.x * EPB;
    int cnt = min(EPB, N_EDGES - e0);          // always a multiple of 4
    const int4* d4 = (const int4*)(ei + N_EDGES + e0);
    for (int k = t; k * 4 < cnt; k += 256) {
        int4 d = d4[k];
        atomicAdd(&hist[d.x >> 8], 1);
        atomicAdd(&hist[d.y >> 8], 1);
        atomicAdd(&hist[d.z >> 8], 1);
        atomicAdd(&hist[d.w >> 8], 1);
    }
    __syncthreads();
    for (int i = t; i < NBUCKET; i += 256)
        counts[i * NBLK + blockIdx.x] = hist[i];
}

// ---------------------------------------------------------------------------
// Single-block pipelined exclusive scan of in[n] -> out[0..n]  (out[n]=total).
// ---------------------------------------------------------------------------
__global__ __launch_bounds__(1024) void scan_full(const int* __restrict__ in,
                                                  int* __restrict__ out, int n) {
    __shared__ int wsum[16];
    __shared__ int woff[16];
    __shared__ int s_carry;
    int t = threadIdx.x, lane = t & 63, w = t >> 6;
    if (t == 0) s_carry = 0;
    int vnext = (t < n) ? in[t] : 0;
    __syncthreads();
    for (int base = 0; base < n; base += 1024) {
        int i = base + t;
        int v = vnext;
        int inext = i + 1024;
        vnext = (inext < n) ? in[inext] : 0;   // prefetch next chunk
        int s = v;
#pragma unroll
        for (int off = 1; off < 64; off <<= 1) {
            int u = __shfl_up(s, off);
            if (lane >= off) s += u;
        }
        if (lane == 63) wsum[w] = s;
        __syncthreads();
        if (t == 0) {
            int acc = 0;
#pragma unroll
            for (int k = 0; k < 16; k++) { woff[k] = acc; acc += wsum[k]; }
            wsum[0] = acc;                      // chunk total
        }
        __syncthreads();
        if (i < n) out[i] = s_carry + woff[w] + s - v;
        __syncthreads();
        if (t == 0) s_carry += wsum[0];
        __syncthreads();
    }
    if (t == 0) out[n] = s_carry;
}

// ---------------------------------------------------------------------------
// Pass A3: scatter packed (src<<16 | dst) into bucket-grouped order.
// ---------------------------------------------------------------------------
__global__ __launch_bounds__(256) void bin_scatter(const int* __restrict__ ei,
                                                   const int* __restrict__ offsets,
                                                   unsigned int* __restrict__ ebin) {
    __shared__ int cur[NBUCKET];
    int t = threadIdx.x;
    for (int i = t; i < NBUCKET; i += 256)
        cur[i] = offsets[i * NBLK + blockIdx.x];
    __syncthreads();
    int e0 = blockIdx.x * EPB;
    int cnt = min(EPB, N_EDGES - e0);
    const int4* s4p = (const int4*)(ei + e0);
    const int4* d4p = (const int4*)(ei + N_EDGES + e0);
    for (int k = t; k * 4 < cnt; k += 256) {
        int4 sv = s4p[k];
        int4 dv = d4p[k];
        int pos;
        pos = atomicAdd(&cur[dv.x >> 8], 1); ebin[pos] = ((unsigned)sv.x << 16) | (unsigned)dv.x;
        pos = atomicAdd(&cur[dv.y >> 8], 1); ebin[pos] = ((unsigned)sv.y << 16) | (unsigned)dv.y;
        pos = atomicAdd(&cur[dv.z >> 8], 1); ebin[pos] = ((unsigned)sv.z << 16) | (unsigned)dv.z;
        pos = atomicAdd(&cur[dv.w >> 8], 1); ebin[pos] = ((unsigned)sv.w << 16) | (unsigned)dv.w;
    }
}

// ---------------------------------------------------------------------------
// Pass B: one block per bucket, fully LDS-resident counting sort.
// ---------------------------------------------------------------------------
__global__ __launch_bounds__(256) void bucket_build(
        const unsigned int* __restrict__ ebin,
        const int* __restrict__ offsets,
        int* __restrict__ rowstart,
        unsigned short* __restrict__ esrc) {
    __shared__ int raw[BCAP];
    __shared__ unsigned short ssrc[BCAP];
    __shared__ int sdeg[256];
    __shared__ int scur[256];
    __shared__ int wsum[4];
    int t = threadIdx.x, lane = t & 63, w = t >> 6;
    int b = blockIdx.x;
    int base = b << 8;
    int nn = min(256, N_NODES - base);
    int bs0 = offsets[b * NBLK];
    int bs1 = (b == NBUCKET - 1) ? N_EDGES : offsets[(b + 1) * NBLK];
    int cnt = min(bs1 - bs0, BCAP);

    sdeg[t] = 0;
    for (int i = t; i < cnt; i += 256) raw[i] = (int)ebin[bs0 + i];
    __syncthreads();
    for (int i = t; i < cnt; i += 256) atomicAdd(&sdeg[raw[i] & 0xff], 1);
    __syncthreads();
    int v = sdeg[t], s = v;
#pragma unroll
    for (int off = 1; off < 64; off <<= 1) {
        int u = __shfl_up(s, off);
        if (lane >= off) s += u;
    }
    if (lane == 63) wsum[w] = s;
    __syncthreads();
    int woff2 = 0;
    for (int k = 0; k < w; k++) woff2 += wsum[k];
    int excl = s - v + woff2;                 // bucket-local exclusive prefix
    if (t < nn) rowstart[base + t] = bs0 + excl;
    scur[t] = excl;
    if (b == NBUCKET - 1 && t == 0) rowstart[N_NODES] = N_EDGES;
    __syncthreads();
    for (int i = t; i < cnt; i += 256) {
        int p = raw[i];
        int pos = atomicAdd(&scur[p & 0xff], 1);
        ssrc[pos] = (unsigned short)(((unsigned)p) >> 16);
    }
    __syncthreads();
    for (int i = t; i < cnt; i += 256)        // coalesced write-out
        esrc[bs0 + i] = ssrc[i];
}

// ---------------------------------------------------------------------------
// Layer 1 fused: neighbor mean of x (6-dim) + linear + relu -> bf16 z.
// ---------------------------------------------------------------------------
__global__ __launch_bounds__(256) void layer1_fused(
        const float* __restrict__ x,
        const int* __restrict__ rowstart,
        const unsigned short* __restrict__ esrc,
        const float* __restrict__ W1l,
        const float* __restrict__ b1,
        const float* __restrict__ W1r,
        unsigned short* __restrict__ z) {
    __shared__ float sWl[IN_DIM * H];
    __shared__ float sWr[IN_DIM * H];
    int t = threadIdx.x;
    for (int i = t; i < IN_DIM * H; i += 256) {
        sWl[i] = W1l[i];
        sWr[i] = W1r[i];
    }
    __syncthreads();

    int wid = t >> 6, lane = t & 63;
    int n = blockIdx.x * 4 + wid;
    if (n >= N_NODES) {                        // zero-row block (blockIdx 12500)
        if (t < H) z[(size_t)N_NODES * H + t] = 0;
        return;
    }
    int r0 = rowstart[n], r1 = rowstart[n + 1];
    int nh = 2 * (r1 - r0);                    // edge-halves
    int half = lane & 1;
    float a0 = 0.f, a1 = 0.f, a2 = 0.f;
    for (int hh = lane; hh < nh; hh += 64) {
        int src = esrc[r0 + (hh >> 1)];
        const float* xs = x + (size_t)src * IN_DIM + half * 3;
        a0 += xs[0]; a1 += xs[1]; a2 += xs[2];
    }
#pragma unroll
    for (int off = 2; off < 64; off <<= 1) {
        a0 += __shfl_xor(a0, off);
        a1 += __shfl_xor(a1, off);
        a2 += __shfl_xor(a2, off);
    }
    float m[IN_DIM];
    m[0] = __shfl(a0, 0); m[1] = __shfl(a1, 0); m[2] = __shfl(a2, 0);
    m[3] = __shfl(a0, 1); m[4] = __shfl(a1, 1); m[5] = __shfl(a2, 1);
    float inv = 1.0f / fmaxf((float)(r1 - r0), 1.0f);

    const float* xn = x + (size_t)n * IN_DIM;
    float acc = b1[lane];
#pragma unroll
    for (int k = 0; k < IN_DIM; k++) {
        acc += m[k] * inv * sWl[k * H + lane] + xn[k] * sWr[k * H + lane];
    }
    z[(size_t)n * H + lane] = f2bf(fmaxf(acc, 0.0f));
}

// ---------------------------------------------------------------------------
// w2prep: one-time transpose+bf16 of W2l/W2r -> Wt[f*64+k] = bf16(W[k*64+f]).
// ---------------------------------------------------------------------------
__global__ __launch_bounds__(256) void w2prep(const float* __restrict__ W2l,
                                              const float* __restrict__ W2r,
                                              unsigned short* __restrict__ Wlt,
                                              unsigned short* __restrict__ Wrt) {
    int t = threadIdx.x;
    for (int i = t; i < H * H; i += 256) {
        int k = i >> 6, f = i & 63;
        Wlt[f * H + k] = f2bf(W2l[i]);
        Wrt[f * H + k] = f2bf(W2r[i]);
    }
}

// ---------------------------------------------------------------------------
// Layer 2, MFMA epilogue, round-7 structure: 16 nodes / block (grid = 3125),
// 4 waves; gather: wave w handles nodes w*4..w*4+3 (proven 4-group ushort4
// pattern, 12500 gather-waves total).  MFMA: wave w computes the 16-node x
// 16-feat tile [all rows, feats w*16..w*16+16]: 4 x mfma_f32_16x16x32_bf16.
// LDS ~23KB -> 6 blocks/CU = 24 waves (75%).
// Layouts (verified): A[m=lane&15][k=quad*8+j]; B[n=lane&15][k=quad*8+j];
// C/D col=lane&15, row=quad*4+reg.
// ---------------------------------------------------------------------------
__global__ __launch_bounds__(256) void layer2_mfma(
        const unsigned short* __restrict__ zin,
        const int* __restrict__ rowstart,
        const unsigned short* __restrict__ esrc,
        const unsigned short* __restrict__ Wlt,
        const float* __restrict__ b2,
        const unsigned short* __restrict__ Wrt,
        float* __restrict__ out) {
    typedef short bf16x8 __attribute__((ext_vector_type(8)));
    typedef float f32x4 __attribute__((ext_vector_type(4)));
    __shared__ __attribute__((aligned(16))) unsigned short smean[16 * L2PAD];
    __shared__ __attribute__((aligned(16))) unsigned short szl[16 * L2PAD];
    __shared__ __attribute__((aligned(16))) unsigned short sWl[64 * L2PAD];
    __shared__ __attribute__((aligned(16))) unsigned short sWr[64 * L2PAD];

    int t = threadIdx.x;
    int w = t >> 6, lane = t & 63;
    int g = lane >> 4, lg = lane & 15;
    int n0 = blockIdx.x * 16;

    // stage pre-transposed bf16 weights (k-consecutive: conflict-free)
    {
        const ushort4* wl4 = (const ushort4*)Wlt;
        const ushort4* wr4 = (const ushort4*)Wrt;
        for (int qi = t; qi < H * H / 4; qi += 256) {
            int f = qi >> 4, kq = qi & 15;
            *(ushort4*)&sWl[f * L2PAD + kq * 4] = wl4[qi];
            *(ushort4*)&sWr[f * L2PAD + kq * 4] = wr4[qi];
        }
    }

    // ---- gather phase: wave w -> nodes w*4 .. w*4+3 ----
    for (int q = 0; q < 4; q++) {
        int ln = w * 4 + q;
        int n = n0 + ln;                       // grid exact: n < 50000 always
        int r0 = rowstart[n], r1 = rowstart[n + 1];
        float4 acc = make_float4(0.f, 0.f, 0.f, 0.f);
        for (int base = r0; base < r1; base += 64) {
            int ii = base + lane;
            int idx = (ii < r1) ? (int)esrc[ii] : N_NODES;   // zero row
            int rem = r1 - base;                             // wave-uniform
#pragma unroll 1
            for (int c = 0; c < 64; c += 16) {
                if (c >= rem) break;                         // wave-uniform
#pragma unroll
                for (int tt = 0; tt < 4; tt++) {
                    int j = c + tt * 4 + g;
                    int s = __shfl(idx, j);
                    const ushort4* zr = (const ushort4*)(zin + (size_t)s * H);
                    ushort4 v = zr[lg];
                    acc.x += bf2f(v.x); acc.y += bf2f(v.y);
                    acc.z += bf2f(v.z); acc.w += bf2f(v.w);
                }
            }
        }
#pragma unroll
        for (int off = 16; off < 64; off <<= 1) {
            acc.x += __shfl_xor(acc.x, off);
            acc.y += __shfl_xor(acc.y, off);
            acc.z += __shfl_xor(acc.z, off);
            acc.w += __shfl_xor(acc.w, off);
        }
        float inv = 1.0f / fmaxf((float)(r1 - r0), 1.0f);
        if (g == 0) {
            ushort4 mb;
            mb.x = f2bf(acc.x * inv); mb.y = f2bf(acc.y * inv);
            mb.z = f2bf(acc.z * inv); mb.w = f2bf(acc.w * inv);
            *(ushort4*)&smean[ln * L2PAD + lg * 4] = mb;
        }
        szl[ln * L2PAD + lane] = zin[(size_t)n * H + lane];
    }
    __syncthreads();

    // ---- MFMA phase: wave w -> feats [16w, 16w+16) for all 16 nodes ----
    f32x4 acc = {0.f, 0.f, 0.f, 0.f};
#pragma unroll
    for (int ks = 0; ks < 2; ks++) {
        int ko = ks * 32 + g * 8;
        bf16x8 aM = *(const bf16x8*)&smean[lg * L2PAD + ko];
        bf16x8 aZ = *(const bf16x8*)&szl[lg * L2PAD + ko];
        bf16x8 bL = *(const bf16x8*)&sWl[(w * 16 + lg) * L2PAD + ko];
        bf16x8 bR = *(const bf16x8*)&sWr[(w * 16 + lg) * L2PAD + ko];
        acc = __builtin_amdgcn_mfma_f32_16x16x32_bf16(aM, bL, acc, 0, 0, 0);
        acc = __builtin_amdgcn_mfma_f32_16x16x32_bf16(aZ, bR, acc, 0, 0, 0);
    }
    float bias = b2[w * 16 + lg];
#pragma unroll
    for (int r = 0; r < 4; r++) {
        int node = n0 + g * 4 + r;
        out[(size_t)node * H + w * 16 + lg] = acc[r] + bias;
    }
}

// ---------------------------------------------------------------------------
extern "C" void kernel_launch(void* const* d_in, const int* in_sizes, int n_in,
                              void* d_out, int out_size, void* d_ws, size_t ws_size,
                              hipStream_t stream) {
    const float* x   = (const float*)d_in[0];
    const int*   ei  = (const int*)d_in[1];   // [2, N_EDGES]
    const float* W1l = (const float*)d_in[2];
    const float* b1  = (const float*)d_in[3];
    const float* W1r = (const float*)d_in[4];
    const float* W2l = (const float*)d_in[5];
    const float* b2  = (const float*)d_in[6];
    const float* W2r = (const float*)d_in[7];
    float* out = (float*)d_out;

    // Workspace layout (keeps 16B alignment for ebin/esrc/z/weights):
    int* counts   = (int*)d_ws;                          // 38416
    int* offsets  = counts + COUNTS_N;                   // 38416 + 8
    int* rowstart = offsets + COUNTS_N + 8;              // 50001 (+pad to 50008)
    unsigned int*   ebin = (unsigned int*)(rowstart + 50008);   // 1600000
    unsigned short* esrc = (unsigned short*)(ebin + N_EDGES);   // 1600000 u16
    unsigned short* z    = esrc + N_EDGES;               // (N_NODES+1)*H bf16
    unsigned short* Wlt  = z + (size_t)(N_NODES + 1) * H;       // 4096 bf16
    unsigned short* Wrt  = Wlt + H * H;                         // 4096 bf16

    // CSR build via bucketed counting sort (LDS atomics only)
    bin_count<<<NBLK, 256, 0, stream>>>(ei, counts);
    scan_full<<<1, 1024, 0, stream>>>(counts, offsets, COUNTS_N);
    bin_scatter<<<NBLK, 256, 0, stream>>>(ei, offsets, ebin);
    bucket_build<<<NBUCKET, 256, 0, stream>>>(ebin, offsets, rowstart, esrc);
    w2prep<<<1, 256, 0, stream>>>(W2l, W2r, Wlt, Wrt);

    // Fused layers (+1 block in layer1 zeroes the dummy z row)
    layer1_fused<<<N_NODES / 4 + 1, 256, 0, stream>>>(x, rowstart, esrc,
                                                      W1l, b1, W1r, z);
    layer2_mfma<<<N_NODES / 16, 256, 0, stream>>>(z, rowstart, esrc,
                                                  Wlt, b2, Wrt, out);
}

// Round 8
// 161.797 us; speedup vs baseline: 4.1194x; 1.2204x over previous
//
#include <hip/hip_runtime.h>

#define N_NODES 50000
#define N_EDGES 1600000
#define IN_DIM 6
#define H 64

#define NBUCKET 196            // dst >> 8  (256 nodes per bucket)
#define NBLK 196               // edge chunks
#define EPB 8192               // edges per chunk (196*8192 >= 1.6M)
#define BCAP 10240             // bucket region capacity (mean 8192, sd ~90)

#define L2PAD 72               // padded LDS row stride (bf16) = 144B

// bf16 helpers (storage-only; all math in fp32)
__device__ __forceinline__ float bf2f(unsigned short u) {
    return __uint_as_float(((unsigned int)u) << 16);
}
__device__ __forceinline__ unsigned short f2bf(float f) {
    unsigned int u = __float_as_uint(f);
    u += 0x7fffu + ((u >> 16) & 1u);   // round-to-nearest-even
    return (unsigned short)(u >> 16);
}

// ---------------------------------------------------------------------------
// Pass A (fused): stage edges in LDS, LDS histogram, reserve bucket ranges
// via ONE global atomicAdd per (block,bucket), scatter from LDS.
// Block NBLK additionally does the W2 transpose prep (no scan kernel needed).
// ebin layout: bucket b owns [b*BCAP, b*BCAP + cnt_b); gcur[b] = cnt_b after.
// ---------------------------------------------------------------------------
__global__ __launch_bounds__(256) void scatter_bucketed(
        const int* __restrict__ ei,
        int* __restrict__ gcur,
        unsigned int* __restrict__ ebin,
        const float* __restrict__ W2l,
        const float* __restrict__ W2r,
        unsigned short* __restrict__ Wlt,
        unsigned short* __restrict__ Wrt) {
    int t = threadIdx.x;
    if (blockIdx.x == NBLK) {                  // w2prep block
        for (int i = t; i < H * H; i += 256) {
            int k = i >> 6, f = i & 63;
            Wlt[f * H + k] = f2bf(W2l[i]);
            Wrt[f * H + k] = f2bf(W2r[i]);
        }
        return;
    }
    __shared__ unsigned int sedge[EPB];        // 32 KB staged edges
    __shared__ int hist[NBUCKET];
    __shared__ int cur[NBUCKET];
    for (int i = t; i < NBUCKET; i += 256) hist[i] = 0;
    __syncthreads();
    int e0 = blockIdx.x * EPB;
    int cnt = min(EPB, N_EDGES - e0);          // multiple of 4
    const int4* s4 = (const int4*)(ei + e0);
    const int4* d4 = (const int4*)(ei + N_EDGES + e0);
    for (int k = t; k * 4 < cnt; k += 256) {
        int4 sv = s4[k];
        int4 dv = d4[k];
        sedge[k * 4 + 0] = ((unsigned)sv.x << 16) | (unsigned)dv.x;
        sedge[k * 4 + 1] = ((unsigned)sv.y << 16) | (unsigned)dv.y;
        sedge[k * 4 + 2] = ((unsigned)sv.z << 16) | (unsigned)dv.z;
        sedge[k * 4 + 3] = ((unsigned)sv.w << 16) | (unsigned)dv.w;
        atomicAdd(&hist[dv.x >> 8], 1);
        atomicAdd(&hist[dv.y >> 8], 1);
        atomicAdd(&hist[dv.z >> 8], 1);
        atomicAdd(&hist[dv.w >> 8], 1);
    }
    __syncthreads();
    // reserve [base, base+hist[i]) in bucket i  (device-scope atomic)
    for (int i = t; i < NBUCKET; i += 256)
        cur[i] = atomicAdd(&gcur[i], hist[i]);
    __syncthreads();
    for (int k = t; k * 4 < cnt; k += 256) {
#pragma unroll
        for (int j = 0; j < 4; j++) {
            unsigned int p = sedge[k * 4 + j];
            int b = (int)(p & 0xffffu) >> 8;
            int pos = atomicAdd(&cur[b], 1);
            if (pos < BCAP) ebin[b * BCAP + pos] = p;
        }
    }
}

// ---------------------------------------------------------------------------
// Pass B: one block per bucket, fully LDS-resident counting sort.
// Writes rowpair[n] = (start, end) absolute offsets into esrc.
// ---------------------------------------------------------------------------
__global__ __launch_bounds__(256) void bucket_build(
        const unsigned int* __restrict__ ebin,
        const int* __restrict__ gcur,
        int2* __restrict__ rowpair,
        unsigned short* __restrict__ esrc) {
    __shared__ int raw[BCAP];
    __shared__ unsigned short ssrc[BCAP];
    __shared__ int sdeg[256];
    __shared__ int scur[256];
    __shared__ int wsum[4];
    int t = threadIdx.x, lane = t & 63, w = t >> 6;
    int b = blockIdx.x;
    int base = b << 8;
    int nn = min(256, N_NODES - base);
    int ebase = b * BCAP;
    int cnt = min(gcur[b], BCAP);

    sdeg[t] = 0;
    for (int i = t; i < cnt; i += 256) raw[i] = (int)ebin[ebase + i];
    __syncthreads();
    for (int i = t; i < cnt; i += 256) atomicAdd(&sdeg[raw[i] & 0xff], 1);
    __syncthreads();
    int v = sdeg[t], s = v;
#pragma unroll
    for (int off = 1; off < 64; off <<= 1) {
        int u = __shfl_up(s, off);
        if (lane >= off) s += u;
    }
    if (lane == 63) wsum[w] = s;
    __syncthreads();
    int woff2 = 0;
    for (int k = 0; k < w; k++) woff2 += wsum[k];
    int excl = s - v + woff2;                 // bucket-local exclusive prefix
    if (t < nn) rowpair[base + t] = make_int2(ebase + excl, ebase + excl + v);
    scur[t] = excl;
    __syncthreads();
    for (int i = t; i < cnt; i += 256) {
        int p = raw[i];
        int pos = atomicAdd(&scur[p & 0xff], 1);
        ssrc[pos] = (unsigned short)(((unsigned)p) >> 16);
    }
    __syncthreads();
    for (int i = t; i < cnt; i += 256)        // coalesced write-out
        esrc[ebase + i] = ssrc[i];
}

// ---------------------------------------------------------------------------
// Layer 1 fused: neighbor mean of x (6-dim) + linear + relu -> bf16 z.
// ---------------------------------------------------------------------------
__global__ __launch_bounds__(256) void layer1_fused(
        const float* __restrict__ x,
        const int2* __restrict__ rowpair,
        const unsigned short* __restrict__ esrc,
        const float* __restrict__ W1l,
        const float* __restrict__ b1,
        const float* __restrict__ W1r,
        unsigned short* __restrict__ z) {
    __shared__ float sWl[IN_DIM * H];
    __shared__ float sWr[IN_DIM * H];
    int t = threadIdx.x;
    for (int i = t; i < IN_DIM * H; i += 256) {
        sWl[i] = W1l[i];
        sWr[i] = W1r[i];
    }
    __syncthreads();

    int wid = t >> 6, lane = t & 63;
    int n = blockIdx.x * 4 + wid;
    if (n >= N_NODES) {                        // zero-row block (blockIdx 12500)
        if (t < H) z[(size_t)N_NODES * H + t] = 0;
        return;
    }
    int2 rp = rowpair[n];
    int r0 = rp.x, r1 = rp.y;
    int nh = 2 * (r1 - r0);                    // edge-halves
    int half = lane & 1;
    float a0 = 0.f, a1 = 0.f, a2 = 0.f;
    for (int hh = lane; hh < nh; hh += 64) {
        int src = esrc[r0 + (hh >> 1)];
        const float* xs = x + (size_t)src * IN_DIM + half * 3;
        a0 += xs[0]; a1 += xs[1]; a2 += xs[2];
    }
#pragma unroll
    for (int off = 2; off < 64; off <<= 1) {
        a0 += __shfl_xor(a0, off);
        a1 += __shfl_xor(a1, off);
        a2 += __shfl_xor(a2, off);
    }
    float m[IN_DIM];
    m[0] = __shfl(a0, 0); m[1] = __shfl(a1, 0); m[2] = __shfl(a2, 0);
    m[3] = __shfl(a0, 1); m[4] = __shfl(a1, 1); m[5] = __shfl(a2, 1);
    float inv = 1.0f / fmaxf((float)(r1 - r0), 1.0f);

    const float* xn = x + (size_t)n * IN_DIM;
    float acc = b1[lane];
#pragma unroll
    for (int k = 0; k < IN_DIM; k++) {
        acc += m[k] * inv * sWl[k * H + lane] + xn[k] * sWr[k * H + lane];
    }
    z[(size_t)n * H + lane] = f2bf(fmaxf(acc, 0.0f));
}

// ---------------------------------------------------------------------------
// Layer 2, MFMA epilogue (round-7 proven structure): 16 nodes / block
// (grid = 3125), 4 waves; wave w gathers nodes w*4..w*4+3; MFMA: wave w
// computes feats [16w,16w+16) for all 16 nodes.
// ---------------------------------------------------------------------------
__global__ __launch_bounds__(256) void layer2_mfma(
        const unsigned short* __restrict__ zin,
        const int2* __restrict__ rowpair,
        const unsigned short* __restrict__ esrc,
        const unsigned short* __restrict__ Wlt,
        const float* __restrict__ b2,
        const unsigned short* __restrict__ Wrt,
        float* __restrict__ out) {
    typedef short bf16x8 __attribute__((ext_vector_type(8)));
    typedef float f32x4 __attribute__((ext_vector_type(4)));
    __shared__ __attribute__((aligned(16))) unsigned short smean[16 * L2PAD];
    __shared__ __attribute__((aligned(16))) unsigned short szl[16 * L2PAD];
    __shared__ __attribute__((aligned(16))) unsigned short sWl[64 * L2PAD];
    __shared__ __attribute__((aligned(16))) unsigned short sWr[64 * L2PAD];

    int t = threadIdx.x;
    int w = t >> 6, lane = t & 63;
    int g = lane >> 4, lg = lane & 15;
    int n0 = blockIdx.x * 16;

    // stage pre-transposed bf16 weights (k-consecutive: conflict-free)
    {
        const ushort4* wl4 = (const ushort4*)Wlt;
        const ushort4* wr4 = (const ushort4*)Wrt;
        for (int qi = t; qi < H * H / 4; qi += 256) {
            int f = qi >> 4, kq = qi & 15;
            *(ushort4*)&sWl[f * L2PAD + kq * 4] = wl4[qi];
            *(ushort4*)&sWr[f * L2PAD + kq * 4] = wr4[qi];
        }
    }

    // ---- gather phase: wave w -> nodes w*4 .. w*4+3 ----
    for (int q = 0; q < 4; q++) {
        int ln = w * 4 + q;
        int n = n0 + ln;                       // grid exact: n < 50000 always
        int2 rp = rowpair[n];
        int r0 = rp.x, r1 = rp.y;
        float4 acc = make_float4(0.f, 0.f, 0.f, 0.f);
        for (int base = r0; base < r1; base += 64) {
            int ii = base + lane;
            int idx = (ii < r1) ? (int)esrc[ii] : N_NODES;   // zero row
            int rem = r1 - base;                             // wave-uniform
#pragma unroll 1
            for (int c = 0; c < 64; c += 16) {
                if (c >= rem) break;                         // wave-uniform
#pragma unroll
                for (int tt = 0; tt < 4; tt++) {
                    int j = c + tt * 4 + g;
                    int s = __shfl(idx, j);
                    const ushort4* zr = (const ushort4*)(zin + (size_t)s * H);
                    ushort4 v = zr[lg];
                    acc.x += bf2f(v.x); acc.y += bf2f(v.y);
                    acc.z += bf2f(v.z); acc.w += bf2f(v.w);
                }
            }
        }
#pragma unroll
        for (int off = 16; off < 64; off <<= 1) {
            acc.x += __shfl_xor(acc.x, off);
            acc.y += __shfl_xor(acc.y, off);
            acc.z += __shfl_xor(acc.z, off);
            acc.w += __shfl_xor(acc.w, off);
        }
        float inv = 1.0f / fmaxf((float)(r1 - r0), 1.0f);
        if (g == 0) {
            ushort4 mb;
            mb.x = f2bf(acc.x * inv); mb.y = f2bf(acc.y * inv);
            mb.z = f2bf(acc.z * inv); mb.w = f2bf(acc.w * inv);
            *(ushort4*)&smean[ln * L2PAD + lg * 4] = mb;
        }
        szl[ln * L2PAD + lane] = zin[(size_t)n * H + lane];
    }
    __syncthreads();

    // ---- MFMA phase: wave w -> feats [16w, 16w+16) for all 16 nodes ----
    f32x4 acc = {0.f, 0.f, 0.f, 0.f};
#pragma unroll
    for (int ks = 0; ks < 2; ks++) {
        int ko = ks * 32 + g * 8;
        bf16x8 aM = *(const bf16x8*)&smean[lg * L2PAD + ko];
        bf16x8 aZ = *(const bf16x8*)&szl[lg * L2PAD + ko];
        bf16x8 bL = *(const bf16x8*)&sWl[(w * 16 + lg) * L2PAD + ko];
        bf16x8 bR = *(const bf16x8*)&sWr[(w * 16 + lg) * L2PAD + ko];
        acc = __builtin_amdgcn_mfma_f32_16x16x32_bf16(aM, bL, acc, 0, 0, 0);
        acc = __builtin_amdgcn_mfma_f32_16x16x32_bf16(aZ, bR, acc, 0, 0, 0);
    }
    float bias = b2[w * 16 + lg];
#pragma unroll
    for (int r = 0; r < 4; r++) {
        int node = n0 + g * 4 + r;
        out[(size_t)node * H + w * 16 + lg] = acc[r] + bias;
    }
}

// ---------------------------------------------------------------------------
extern "C" void kernel_launch(void* const* d_in, const int* in_sizes, int n_in,
                              void* d_out, int out_size, void* d_ws, size_t ws_size,
                              hipStream_t stream) {
    const float* x   = (const float*)d_in[0];
    const int*   ei  = (const int*)d_in[1];   // [2, N_EDGES]
    const float* W1l = (const float*)d_in[2];
    const float* b1  = (const float*)d_in[3];
    const float* W1r = (const float*)d_in[4];
    const float* W2l = (const float*)d_in[5];
    const float* b2  = (const float*)d_in[6];
    const float* W2r = (const float*)d_in[7];
    float* out = (float*)d_out;

    // Workspace layout (keeps 16B alignment for ebin/esrc/z/weights):
    int* gcur = (int*)d_ws;                              // 196 (+pad to 208)
    int2* rowpair = (int2*)(gcur + 208);                 // 50000 int2
    unsigned int*   ebin = (unsigned int*)(rowpair + N_NODES);  // 196*10240 u32
    unsigned short* esrc = (unsigned short*)(ebin + NBUCKET * BCAP);  // u16
    unsigned short* z    = esrc + NBUCKET * BCAP;        // (N_NODES+1)*H bf16
    unsigned short* Wlt  = z + (size_t)(N_NODES + 1) * H;       // 4096 bf16
    unsigned short* Wrt  = Wlt + H * H;                         // 4096 bf16

    hipMemsetAsync(gcur, 0, NBUCKET * sizeof(int), stream);

    // CSR build: fused count+reserve+scatter (+w2prep block), then bucket sort
    scatter_bucketed<<<NBLK + 1, 256, 0, stream>>>(ei, gcur, ebin,
                                                   W2l, W2r, Wlt, Wrt);
    bucket_build<<<NBUCKET, 256, 0, stream>>>(ebin, gcur, rowpair, esrc);

    // Fused layers (+1 block in layer1 zeroes the dummy z row)
    layer1_fused<<<N_NODES / 4 + 1, 256, 0, stream>>>(x, rowpair, esrc,
                                                      W1l, b1, W1r, z);
    layer2_mfma<<<N_NODES / 16, 256, 0, stream>>>(z, rowpair, esrc,
                                                  Wlt, b2, Wrt, out);
}

// Round 9
// 152.225 us; speedup vs baseline: 4.3784x; 1.0629x over previous
//
#include <hip/hip_runtime.h>

#define N_NODES 50000
#define N_EDGES 1600000
#define IN_DIM 6
#define H 64

#define NBUCKET 196            // dst >> 8  (256 nodes per bucket)
#define NBLK 196               // edge chunks
#define EPB 8192               // edges per chunk (196*8192 >= 1.6M)
#define BCAP 9216              // bucket capacity: mean 8163, sd ~90 -> +11.6 sd

#define L2PAD 72               // padded LDS row stride (bf16) = 144B

// bf16 helpers (storage-only; all math in fp32)
__device__ __forceinline__ float bf2f(unsigned short u) {
    return __uint_as_float(((unsigned int)u) << 16);
}
__device__ __forceinline__ unsigned short f2bf(float f) {
    unsigned int u = __float_as_uint(f);
    u += 0x7fffu + ((u >> 16) & 1u);   // round-to-nearest-even
    return (unsigned short)(u >> 16);
}

// ---------------------------------------------------------------------------
// Pass A (fused): stage edges in LDS, LDS histogram, reserve bucket ranges
// via ONE global atomicAdd per (block,bucket), scatter from LDS.
// Extra block NBLK does the W2 transpose prep + zeroes z's dummy row.
// ---------------------------------------------------------------------------
__global__ __launch_bounds__(256) void scatter_bucketed(
        const int* __restrict__ ei,
        int* __restrict__ gcur,
        unsigned int* __restrict__ ebin,
        const float* __restrict__ W2l,
        const float* __restrict__ W2r,
        unsigned short* __restrict__ Wlt,
        unsigned short* __restrict__ Wrt,
        unsigned short* __restrict__ z) {
    int t = threadIdx.x;
    if (blockIdx.x == NBLK) {                  // w2prep + z zero-row block
        for (int i = t; i < H * H; i += 256) {
            int k = i >> 6, f = i & 63;
            Wlt[f * H + k] = f2bf(W2l[i]);
            Wrt[f * H + k] = f2bf(W2r[i]);
        }
        if (t < H) z[(size_t)N_NODES * H + t] = 0;
        return;
    }
    __shared__ unsigned int sedge[EPB];        // 32 KB staged edges
    __shared__ int hist[NBUCKET];
    __shared__ int cur[NBUCKET];
    for (int i = t; i < NBUCKET; i += 256) hist[i] = 0;
    __syncthreads();
    int e0 = blockIdx.x * EPB;
    int cnt = min(EPB, N_EDGES - e0);          // multiple of 4
    const int4* s4 = (const int4*)(ei + e0);
    const int4* d4 = (const int4*)(ei + N_EDGES + e0);
    for (int k = t; k * 4 < cnt; k += 256) {
        int4 sv = s4[k];
        int4 dv = d4[k];
        sedge[k * 4 + 0] = ((unsigned)sv.x << 16) | (unsigned)dv.x;
        sedge[k * 4 + 1] = ((unsigned)sv.y << 16) | (unsigned)dv.y;
        sedge[k * 4 + 2] = ((unsigned)sv.z << 16) | (unsigned)dv.z;
        sedge[k * 4 + 3] = ((unsigned)sv.w << 16) | (unsigned)dv.w;
        atomicAdd(&hist[dv.x >> 8], 1);
        atomicAdd(&hist[dv.y >> 8], 1);
        atomicAdd(&hist[dv.z >> 8], 1);
        atomicAdd(&hist[dv.w >> 8], 1);
    }
    __syncthreads();
    for (int i = t; i < NBUCKET; i += 256)
        cur[i] = atomicAdd(&gcur[i], hist[i]);
    __syncthreads();
    for (int k = t; k * 4 < cnt; k += 256) {
#pragma unroll
        for (int j = 0; j < 4; j++) {
            unsigned int p = sedge[k * 4 + j];
            int b = (int)(p & 0xffffu) >> 8;
            int pos = atomicAdd(&cur[b], 1);
            if (pos < BCAP) ebin[(size_t)b * BCAP + pos] = p;
        }
    }
}

// ---------------------------------------------------------------------------
// Pass B + Layer 1 fused: one block (512 thr) per bucket.
//   1. LDS counting sort of the bucket's edges -> ssrc, rowpair, esrc
//   2. layer-1 x-gather straight from LDS ssrc (node-per-thread-pair)
//   3. linear phase: feat-per-thread, weights hoisted to registers,
//      broadcast ds_read_b128 of the per-node mean/self rows -> bf16 z
// Static LDS = 61.5 KB (raw region reused for smx/spart after the sort).
// ---------------------------------------------------------------------------
__global__ __launch_bounds__(512) void bucket_layer1(
        const unsigned int* __restrict__ ebin,
        const int* __restrict__ gcur,
        const float* __restrict__ x,
        const float* __restrict__ W1l,
        const float* __restrict__ b1,
        const float* __restrict__ W1r,
        int2* __restrict__ rowpair,
        unsigned short* __restrict__ esrc,
        unsigned short* __restrict__ z) {
    __shared__ int raw[BCAP];                  // 36864 B (aliased below)
    __shared__ unsigned short ssrc[BCAP];      // 18432 B
    __shared__ int sdeg[256];
    __shared__ int sstart[256];
    __shared__ int scur[256];
    __shared__ int wsum[4];
    __shared__ float sW1l[IN_DIM * H];         // 1536 B
    __shared__ float sW1r[IN_DIM * H];         // 1536 B
    float* smx   = (float*)raw;                // [256][16]: mean 0..5, self 6..11
    float* spart = (float*)raw + 4096;         // [256][6] half-1 partials

    int t = threadIdx.x;
    int lane = t & 63, w = t >> 6;
    int b = blockIdx.x;
    int base = b << 8;
    int nn = min(256, N_NODES - base);         // last bucket has 80 nodes
    int ebase = b * BCAP;
    int cnt = min(gcur[b], BCAP);

    if (t < 256) sdeg[t] = 0;
    for (int i = t; i < IN_DIM * H; i += 512) { sW1l[i] = W1l[i]; sW1r[i] = W1r[i]; }
    for (int i = t; i < cnt; i += 512) raw[i] = (int)ebin[ebase + i];
    __syncthreads();
    for (int i = t; i < cnt; i += 512) atomicAdd(&sdeg[raw[i] & 0xff], 1);
    __syncthreads();
    int v = 0, s = 0;
    if (t < 256) {                              // waves 0..3: scan of 256 bins
        v = sdeg[t]; s = v;
#pragma unroll
        for (int off = 1; off < 64; off <<= 1) {
            int u = __shfl_up(s, off);
            if (lane >= off) s += u;
        }
        if (lane == 63) wsum[w] = s;
    }
    __syncthreads();
    if (t < 256) {
        int woff = 0;
        for (int k = 0; k < w; k++) woff += wsum[k];
        int excl = s - v + woff;                // bucket-local exclusive prefix
        sstart[t] = excl;
        scur[t] = excl;
        if (t < nn) rowpair[base + t] = make_int2(ebase + excl, ebase + excl + v);
    }
    __syncthreads();
    for (int i = t; i < cnt; i += 512) {        // in-LDS scatter (sort)
        int p = raw[i];
        int pos = atomicAdd(&scur[p & 0xff], 1);
        ssrc[pos] = (unsigned short)((unsigned)p >> 16);
    }
    __syncthreads();
    // raw[] dead from here on: smx/spart alias it.
    for (int i = t; i < cnt; i += 512)          // coalesced esrc write (layer2)
        esrc[ebase + i] = ssrc[i];
    for (int i = t; i < nn * IN_DIM; i += 512) {  // stage self x rows (contig)
        int node = i / 6, k = i - node * 6;
        smx[node * 16 + 6 + k] = x[(size_t)base * IN_DIM + i];
    }

    // ---- layer-1 gather: node-per-thread-pair, each edge read once ----
    int node = t & 255, half = t >> 8;
    float a0 = 0.f, a1 = 0.f, a2 = 0.f, a3 = 0.f, a4 = 0.f, a5 = 0.f;
    int deg = 0, st = 0;
    if (node < nn) { deg = sdeg[node]; st = sstart[node]; }
    for (int i = st + half; i < st + deg; i += 2) {
        int src = ssrc[i];
        const float2* xs = (const float2*)(x + (size_t)src * IN_DIM);
        float2 p0 = xs[0], p1 = xs[1], p2 = xs[2];
        a0 += p0.x; a1 += p0.y; a2 += p1.x;
        a3 += p1.y; a4 += p2.x; a5 += p2.y;
    }
    if (half == 1 && node < nn) {
        spart[node * 6 + 0] = a0; spart[node * 6 + 1] = a1;
        spart[node * 6 + 2] = a2; spart[node * 6 + 3] = a3;
        spart[node * 6 + 4] = a4; spart[node * 6 + 5] = a5;
    }
    __syncthreads();
    if (half == 0 && node < nn) {
        float inv = 1.0f / fmaxf((float)deg, 1.0f);
        smx[node * 16 + 0] = (a0 + spart[node * 6 + 0]) * inv;
        smx[node * 16 + 1] = (a1 + spart[node * 6 + 1]) * inv;
        smx[node * 16 + 2] = (a2 + spart[node * 6 + 2]) * inv;
        smx[node * 16 + 3] = (a3 + spart[node * 6 + 3]) * inv;
        smx[node * 16 + 4] = (a4 + spart[node * 6 + 4]) * inv;
        smx[node * 16 + 5] = (a5 + spart[node * 6 + 5]) * inv;
    }
    __syncthreads();

    // ---- layer-1 linear: feat-per-thread, weights in registers ----
    int feat = t & 63, ng = t >> 6;             // 8 node-groups
    float wl[IN_DIM], wr[IN_DIM];
#pragma unroll
    for (int k = 0; k < IN_DIM; k++) { wl[k] = sW1l[k * H + feat]; wr[k] = sW1r[k * H + feat]; }
    float bias = b1[feat];
    for (int nb = ng; nb < nn; nb += 8) {
        const float4* row = (const float4*)&smx[nb * 16];  // broadcast reads
        float4 r0 = row[0], r1 = row[1], r2 = row[2];
        float acc = bias;
        acc += r0.x * wl[0] + r0.y * wl[1] + r0.z * wl[2]
             + r0.w * wl[3] + r1.x * wl[4] + r1.y * wl[5];
        acc += r1.z * wr[0] + r1.w * wr[1] + r2.x * wr[2]
             + r2.y * wr[3] + r2.z * wr[4] + r2.w * wr[5];
        z[(size_t)(base + nb) * H + feat] = f2bf(fmaxf(acc, 0.0f));
    }
}

// ---------------------------------------------------------------------------
// Layer 2, MFMA epilogue (round-7 proven structure): 16 nodes / block
// (grid = 3125), 4 waves; wave w gathers nodes w*4..w*4+3; MFMA: wave w
// computes feats [16w,16w+16) for all 16 nodes.
// ---------------------------------------------------------------------------
__global__ __launch_bounds__(256) void layer2_mfma(
        const unsigned short* __restrict__ zin,
        const int2* __restrict__ rowpair,
        const unsigned short* __restrict__ esrc,
        const unsigned short* __restrict__ Wlt,
        const float* __restrict__ b2,
        const unsigned short* __restrict__ Wrt,
        float* __restrict__ out) {
    typedef short bf16x8 __attribute__((ext_vector_type(8)));
    typedef float f32x4 __attribute__((ext_vector_type(4)));
    __shared__ __attribute__((aligned(16))) unsigned short smean[16 * L2PAD];
    __shared__ __attribute__((aligned(16))) unsigned short szl[16 * L2PAD];
    __shared__ __attribute__((aligned(16))) unsigned short sWl[64 * L2PAD];
    __shared__ __attribute__((aligned(16))) unsigned short sWr[64 * L2PAD];

    int t = threadIdx.x;
    int w = t >> 6, lane = t & 63;
    int g = lane >> 4, lg = lane & 15;
    int n0 = blockIdx.x * 16;

    // stage pre-transposed bf16 weights (k-consecutive: conflict-free)
    {
        const ushort4* wl4 = (const ushort4*)Wlt;
        const ushort4* wr4 = (const ushort4*)Wrt;
        for (int qi = t; qi < H * H / 4; qi += 256) {
            int f = qi >> 4, kq = qi & 15;
            *(ushort4*)&sWl[f * L2PAD + kq * 4] = wl4[qi];
            *(ushort4*)&sWr[f * L2PAD + kq * 4] = wr4[qi];
        }
    }

    // ---- gather phase: wave w -> nodes w*4 .. w*4+3 ----
    for (int q = 0; q < 4; q++) {
        int ln = w * 4 + q;
        int n = n0 + ln;                       // grid exact: n < 50000 always
        int2 rp = rowpair[n];
        int r0 = rp.x, r1 = rp.y;
        float4 acc = make_float4(0.f, 0.f, 0.f, 0.f);
        for (int base = r0; base < r1; base += 64) {
            int ii = base + lane;
            int idx = (ii < r1) ? (int)esrc[ii] : N_NODES;   // zero row
            int rem = r1 - base;                             // wave-uniform
#pragma unroll 1
            for (int c = 0; c < 64; c += 16) {
                if (c >= rem) break;                         // wave-uniform
#pragma unroll
                for (int tt = 0; tt < 4; tt++) {
                    int j = c + tt * 4 + g;
                    int s = __shfl(idx, j);
                    const ushort4* zr = (const ushort4*)(zin + (size_t)s * H);
                    ushort4 vv = zr[lg];
                    acc.x += bf2f(vv.x); acc.y += bf2f(vv.y);
                    acc.z += bf2f(vv.z); acc.w += bf2f(vv.w);
                }
            }
        }
#pragma unroll
        for (int off = 16; off < 64; off <<= 1) {
            acc.x += __shfl_xor(acc.x, off);
            acc.y += __shfl_xor(acc.y, off);
            acc.z += __shfl_xor(acc.z, off);
            acc.w += __shfl_xor(acc.w, off);
        }
        float inv = 1.0f / fmaxf((float)(r1 - r0), 1.0f);
        if (g == 0) {
            ushort4 mb;
            mb.x = f2bf(acc.x * inv); mb.y = f2bf(acc.y * inv);
            mb.z = f2bf(acc.z * inv); mb.w = f2bf(acc.w * inv);
            *(ushort4*)&smean[ln * L2PAD + lg * 4] = mb;
        }
        szl[ln * L2PAD + lane] = zin[(size_t)n * H + lane];
    }
    __syncthreads();

    // ---- MFMA phase: wave w -> feats [16w, 16w+16) for all 16 nodes ----
    f32x4 acc = {0.f, 0.f, 0.f, 0.f};
#pragma unroll
    for (int ks = 0; ks < 2; ks++) {
        int ko = ks * 32 + g * 8;
        bf16x8 aM = *(const bf16x8*)&smean[lg * L2PAD + ko];
        bf16x8 aZ = *(const bf16x8*)&szl[lg * L2PAD + ko];
        bf16x8 bL = *(const bf16x8*)&sWl[(w * 16 + lg) * L2PAD + ko];
        bf16x8 bR = *(const bf16x8*)&sWr[(w * 16 + lg) * L2PAD + ko];
        acc = __builtin_amdgcn_mfma_f32_16x16x32_bf16(aM, bL, acc, 0, 0, 0);
        acc = __builtin_amdgcn_mfma_f32_16x16x32_bf16(aZ, bR, acc, 0, 0, 0);
    }
    float bias = b2[w * 16 + lg];
#pragma unroll
    for (int r = 0; r < 4; r++) {
        int node = n0 + g * 4 + r;
        out[(size_t)node * H + w * 16 + lg] = acc[r] + bias;
    }
}

// ---------------------------------------------------------------------------
extern "C" void kernel_launch(void* const* d_in, const int* in_sizes, int n_in,
                              void* d_out, int out_size, void* d_ws, size_t ws_size,
                              hipStream_t stream) {
    const float* x   = (const float*)d_in[0];
    const int*   ei  = (const int*)d_in[1];   // [2, N_EDGES]
    const float* W1l = (const float*)d_in[2];
    const float* b1  = (const float*)d_in[3];
    const float* W1r = (const float*)d_in[4];
    const float* W2l = (const float*)d_in[5];
    const float* b2  = (const float*)d_in[6];
    const float* W2r = (const float*)d_in[7];
    float* out = (float*)d_out;

    // Workspace layout (keeps 16B alignment for ebin/esrc/z/weights):
    int* gcur = (int*)d_ws;                              // 196 (+pad to 208)
    int2* rowpair = (int2*)(gcur + 208);                 // 50000 int2
    unsigned int*   ebin = (unsigned int*)(rowpair + N_NODES);  // 196*9216 u32
    unsigned short* esrc = (unsigned short*)(ebin + (size_t)NBUCKET * BCAP);
    unsigned short* z    = esrc + (size_t)NBUCKET * BCAP;  // (N_NODES+1)*H bf16
    unsigned short* Wlt  = z + (size_t)(N_NODES + 1) * H;  // 4096 bf16
    unsigned short* Wrt  = Wlt + H * H;                    // 4096 bf16

    hipMemsetAsync(gcur, 0, NBUCKET * sizeof(int), stream);

    // CSR build + layer1 (fused), then layer2
    scatter_bucketed<<<NBLK + 1, 256, 0, stream>>>(ei, gcur, ebin,
                                                   W2l, W2r, Wlt, Wrt, z);
    bucket_layer1<<<NBUCKET, 512, 0, stream>>>(ebin, gcur, x, W1l, b1, W1r,
                                               rowpair, esrc, z);
    layer2_mfma<<<N_NODES / 16, 256, 0, stream>>>(z, rowpair, esrc,
                                                  Wlt, b2, Wrt, out);
}